// Round 1
// baseline (1792.113 us; speedup 1.0000x reference)
//
#include <hip/hip_runtime.h>

// GCN: 2x (linear -> deg-normalized scatter-add -> bias -> tanh) -> linear(1) -> softmax(N)
// Strategy: build CSR by destination once per call (no atomics in the heavy phase),
// wave-per-node gather aggregation, fp32 throughout.

__global__ __launch_bounds__(256) void count_deg(const int* __restrict__ col, int E,
                                                 int* __restrict__ deg) {
    int e = blockIdx.x * 256 + threadIdx.x;
    if (e < E) atomicAdd(&deg[col[e]], 1);
}

__global__ __launch_bounds__(256) void compute_dinv(const int* __restrict__ deg,
                                                    float* __restrict__ dinv, int n) {
    int i = blockIdx.x * 256 + threadIdx.x;
    if (i < n) dinv[i] = 1.0f / sqrtf((float)(deg[i] + 1));  // +1 self loop, always > 0
}

// exclusive scan of deg (edge-only counts) -> rowptr, 3-kernel hierarchy
__global__ __launch_bounds__(256) void scan_blocks(const int* __restrict__ deg, int n,
                                                   int* __restrict__ rowptr,
                                                   int* __restrict__ partial) {
    __shared__ int s[256];
    int t = threadIdx.x;
    int i = blockIdx.x * 256 + t;
    int v = (i < n) ? deg[i] : 0;
    s[t] = v;
    __syncthreads();
    for (int d = 1; d < 256; d <<= 1) {
        int x = (t >= d) ? s[t - d] : 0;
        __syncthreads();
        s[t] += x;
        __syncthreads();
    }
    if (i < n) rowptr[i] = s[t] - v;  // exclusive within block
    if (t == 255) partial[blockIdx.x] = s[255];
}

__global__ void scan_partials(int* partial, int nb) {
    __shared__ int s[512];
    int t = threadIdx.x;
    int v = (t < nb) ? partial[t] : 0;
    s[t] = v;
    __syncthreads();
    for (int d = 1; d < 512; d <<= 1) {
        int x = (t >= d) ? s[t - d] : 0;
        __syncthreads();
        s[t] += x;
        __syncthreads();
    }
    if (t < nb) partial[t] = s[t] - v;  // exclusive block offsets
}

__global__ __launch_bounds__(256) void add_offsets(int* __restrict__ rowptr,
                                                   const int* __restrict__ partial,
                                                   int n, int E) {
    int i = blockIdx.x * 256 + threadIdx.x;
    if (i < n) rowptr[i] += partial[blockIdx.x];
    if (i == 0) rowptr[n] = E;
}

__global__ __launch_bounds__(256) void fill_csr(const int* __restrict__ row,
                                                const int* __restrict__ col, int E,
                                                const int* __restrict__ rowptr,
                                                int* __restrict__ cursor,
                                                const float* __restrict__ dinv,
                                                float2* __restrict__ csr) {
    int e = blockIdx.x * 256 + threadIdx.x;
    if (e >= E) return;
    int r = row[e], c = col[e];
    int slot = rowptr[c] + atomicAdd(&cursor[c], 1);
    csr[slot] = make_float2(__int_as_float(r), dinv[r]);
}

// C[n,128] = A[n,128] @ W[128,128]; W staged in LDS; 64 rows/block, 256 thr, 32 out/thr
__global__ __launch_bounds__(256) void gemm128(const float* __restrict__ A,
                                               const float* __restrict__ W,
                                               float* __restrict__ C, int n) {
    __shared__ float Ws[128 * 128];
    int tid = threadIdx.x;
    const float4* W4 = (const float4*)W;
    float4* Ws4 = (float4*)Ws;
#pragma unroll
    for (int i = 0; i < 16; i++) Ws4[tid + 256 * i] = W4[tid + 256 * i];
    __syncthreads();

    int r0 = blockIdx.x * 64;
    int tr = tid >> 4;   // 0..15
    int tc = tid & 15;   // col group: cols tc*8 .. tc*8+7
    float acc[4][8] = {};

    for (int kc = 0; kc < 128; kc += 16) {
        float4 a[4][4];
#pragma unroll
        for (int rr = 0; rr < 4; rr++) {
            int r = r0 + tr + rr * 16;
            if (r < n) {
                const float4* Ar = (const float4*)&A[r * 128 + kc];
                a[rr][0] = Ar[0]; a[rr][1] = Ar[1]; a[rr][2] = Ar[2]; a[rr][3] = Ar[3];
            } else {
                a[rr][0] = a[rr][1] = a[rr][2] = a[rr][3] = make_float4(0, 0, 0, 0);
            }
        }
#pragma unroll
        for (int kk = 0; kk < 16; kk++) {
            float4 w0 = Ws4[((kc + kk) * 128 + tc * 8) >> 2];
            float4 w1 = Ws4[(((kc + kk) * 128 + tc * 8) >> 2) + 1];
#pragma unroll
            for (int rr = 0; rr < 4; rr++) {
                float av = ((const float*)&a[rr][0])[kk];
                acc[rr][0] += av * w0.x; acc[rr][1] += av * w0.y;
                acc[rr][2] += av * w0.z; acc[rr][3] += av * w0.w;
                acc[rr][4] += av * w1.x; acc[rr][5] += av * w1.y;
                acc[rr][6] += av * w1.z; acc[rr][7] += av * w1.w;
            }
        }
    }
#pragma unroll
    for (int rr = 0; rr < 4; rr++) {
        int r = r0 + tr + rr * 16;
        if (r < n) {
            float4* Cp = (float4*)&C[r * 128 + tc * 8];
            Cp[0] = make_float4(acc[rr][0], acc[rr][1], acc[rr][2], acc[rr][3]);
            Cp[1] = make_float4(acc[rr][4], acc[rr][5], acc[rr][6], acc[rr][7]);
        }
    }
}

// one wave per destination node; acc in registers; out = tanh(dinv[c]*(sum + dinv[c]*t[c]) + b)
__global__ __launch_bounds__(256) void aggregate(const float* __restrict__ T,
                                                 const float2* __restrict__ csr,
                                                 const int* __restrict__ rowptr,
                                                 const float* __restrict__ dinv,
                                                 const float* __restrict__ bias,
                                                 float* __restrict__ Out, int n) {
    int node = (int)((blockIdx.x * 256 + threadIdx.x) >> 6);
    int lane = threadIdx.x & 63;
    if (node >= n) return;
    float di = dinv[node];
    float2 t = *(const float2*)&T[node * 128 + lane * 2];
    float ax = t.x * di, ay = t.y * di;  // self loop (× di again at end)
    int beg = rowptr[node], end = rowptr[node + 1];
    for (int e = beg; e < end; e++) {
        float2 sw = csr[e];  // (src, dinv[src]) — wave-uniform address, broadcast
        int src = __float_as_int(sw.x);
        float w = sw.y;
        float2 ts = *(const float2*)&T[src * 128 + lane * 2];
        ax += w * ts.x;
        ay += w * ts.y;
    }
    float bx = bias[lane * 2], by = bias[lane * 2 + 1];
    ax = tanhf(ax * di + bx);
    ay = tanhf(ay * di + by);
    *(float2*)&Out[node * 128 + lane * 2] = make_float2(ax, ay);
}

__global__ __launch_bounds__(256) void logits_kernel(const float* __restrict__ H,
                                                     const float* __restrict__ Wc,
                                                     const float* __restrict__ bc,
                                                     float* __restrict__ logits,
                                                     unsigned int* __restrict__ maxkey,
                                                     int n) {
    int node = (int)((blockIdx.x * 256 + threadIdx.x) >> 6);
    int lane = threadIdx.x & 63;
    if (node >= n) return;
    float2 h = *(const float2*)&H[node * 128 + lane * 2];
    float2 w = *(const float2*)&Wc[lane * 2];
    float d = h.x * w.x + h.y * w.y;
#pragma unroll
    for (int off = 32; off; off >>= 1) d += __shfl_xor(d, off);
    if (lane == 0) {
        float l = d + bc[0];
        logits[node] = l;
        unsigned int b = __float_as_uint(l);
        unsigned int key = (b & 0x80000000u) ? ~b : (b | 0x80000000u);
        atomicMax(maxkey, key);
    }
}

__global__ __launch_bounds__(256) void exp_kernel(const float* __restrict__ logits,
                                                  const unsigned int* __restrict__ maxkey,
                                                  float* __restrict__ outv,
                                                  float* __restrict__ denom, int n) {
    __shared__ float s[256];
    int i = blockIdx.x * 256 + threadIdx.x;
    unsigned int k = *maxkey;
    float maxv = __uint_as_float((k & 0x80000000u) ? (k ^ 0x80000000u) : ~k);
    float e = 0.0f;
    if (i < n) {
        e = expf(logits[i] - maxv);
        outv[i] = e;
    }
    s[threadIdx.x] = e;
    __syncthreads();
    for (int d = 128; d; d >>= 1) {
        if (threadIdx.x < d) s[threadIdx.x] += s[threadIdx.x + d];
        __syncthreads();
    }
    if (threadIdx.x == 0) atomicAdd(denom, s[0]);
}

__global__ __launch_bounds__(256) void norm_kernel(float* __restrict__ out,
                                                   const float* __restrict__ denom, int n) {
    int i = blockIdx.x * 256 + threadIdx.x;
    if (i < n) out[i] = out[i] / (*denom);
}

extern "C" void kernel_launch(void* const* d_in, const int* in_sizes, int n_in,
                              void* d_out, int out_size, void* d_ws, size_t ws_size,
                              hipStream_t stream) {
    const float* x  = (const float*)d_in[0];
    const int*   ei = (const int*)d_in[1];   // [2,E] int32 (JAX x64 disabled)
    const float* W1 = (const float*)d_in[2];
    const float* b1 = (const float*)d_in[3];
    const float* W2 = (const float*)d_in[4];
    const float* b2 = (const float*)d_in[5];
    const float* Wc = (const float*)d_in[6];
    const float* bc = (const float*)d_in[7];

    int n = in_sizes[0] / 128;
    int E = in_sizes[1] / 2;
    const int* row = ei;
    const int* col = ei + E;

    char* ws = (char*)d_ws;
    size_t off = 0;
    auto alloc = [&](size_t bytes) -> void* {
        void* p = ws + off;
        off += (bytes + 255) & ~(size_t)255;
        return p;
    };
    float*  A      = (float*)alloc((size_t)n * 128 * 4);
    float*  B      = (float*)alloc((size_t)n * 128 * 4);
    float*  dinv   = (float*)alloc((size_t)n * 4);
    int*    deg    = (int*)alloc((size_t)n * 4);
    int*    cursor = (int*)alloc((size_t)n * 4);
    int*    rowptr = (int*)alloc((size_t)(n + 1) * 4);
    int*    partial= (int*)alloc((size_t)((n + 255) / 256) * 4);
    float2* csr    = (float2*)alloc((size_t)E * 8);
    float*  logits = (float*)alloc((size_t)n * 4);
    unsigned int* maxkey = (unsigned int*)alloc(4);
    float*  denom  = (float*)alloc(4);

    int nbN = (n + 255) / 256;
    int nbE = (E + 255) / 256;
    int nbW = (n + 3) / 4;  // 4 waves (nodes) per 256-thread block

    hipMemsetAsync(deg, 0, (size_t)n * 4, stream);
    hipMemsetAsync(cursor, 0, (size_t)n * 4, stream);
    hipMemsetAsync(maxkey, 0, 4, stream);
    hipMemsetAsync(denom, 0, 4, stream);

    count_deg<<<nbE, 256, 0, stream>>>(col, E, deg);
    compute_dinv<<<nbN, 256, 0, stream>>>(deg, dinv, n);
    scan_blocks<<<nbN, 256, 0, stream>>>(deg, n, rowptr, partial);
    scan_partials<<<1, 512, 0, stream>>>(partial, nbN);
    add_offsets<<<nbN, 256, 0, stream>>>(rowptr, partial, n, E);
    fill_csr<<<nbE, 256, 0, stream>>>(row, col, E, rowptr, cursor, dinv, csr);

    gemm128<<<(n + 63) / 64, 256, 0, stream>>>(x, W1, A, n);
    aggregate<<<nbW, 256, 0, stream>>>(A, csr, rowptr, dinv, b1, B, n);
    gemm128<<<(n + 63) / 64, 256, 0, stream>>>(B, W2, A, n);
    aggregate<<<nbW, 256, 0, stream>>>(A, csr, rowptr, dinv, b2, B, n);

    logits_kernel<<<nbW, 256, 0, stream>>>(B, Wc, bc, logits, maxkey, n);
    exp_kernel<<<nbN, 256, 0, stream>>>(logits, maxkey, (float*)d_out, denom, n);
    norm_kernel<<<nbN, 256, 0, stream>>>((float*)d_out, denom, n);
}

// Round 2
// 653.459 us; speedup vs baseline: 2.7425x; 2.7425x over previous
//
#include <hip/hip_runtime.h>

// GCN: 2x (linear -> deg-normalized scatter-add -> bias -> tanh) -> linear(1) -> softmax(N)
// CSR built per call (no atomics in heavy phase); wave-per-node gather aggregation.
// R1: logits fused into 2nd aggregate (kills 100K same-address atomicMax = 1.1ms);
//     softmax max via deterministic 2-stage reduction.

__global__ __launch_bounds__(256) void count_deg(const int* __restrict__ col, int E,
                                                 int* __restrict__ deg) {
    int e = blockIdx.x * 256 + threadIdx.x;
    if (e < E) atomicAdd(&deg[col[e]], 1);
}

__global__ __launch_bounds__(256) void compute_dinv(const int* __restrict__ deg,
                                                    float* __restrict__ dinv, int n) {
    int i = blockIdx.x * 256 + threadIdx.x;
    if (i < n) dinv[i] = 1.0f / sqrtf((float)(deg[i] + 1));  // +1 self loop, always > 0
}

// exclusive scan of deg -> rowptr (3-kernel hierarchy; nbN=391 <= 512)
__global__ __launch_bounds__(256) void scan_blocks(const int* __restrict__ deg, int n,
                                                   int* __restrict__ rowptr,
                                                   int* __restrict__ partial) {
    __shared__ int s[256];
    int t = threadIdx.x;
    int i = blockIdx.x * 256 + t;
    int v = (i < n) ? deg[i] : 0;
    s[t] = v;
    __syncthreads();
    for (int d = 1; d < 256; d <<= 1) {
        int x = (t >= d) ? s[t - d] : 0;
        __syncthreads();
        s[t] += x;
        __syncthreads();
    }
    if (i < n) rowptr[i] = s[t] - v;
    if (t == 255) partial[blockIdx.x] = s[255];
}

__global__ void scan_partials(int* partial, int nb) {
    __shared__ int s[512];
    int t = threadIdx.x;
    int v = (t < nb) ? partial[t] : 0;
    s[t] = v;
    __syncthreads();
    for (int d = 1; d < 512; d <<= 1) {
        int x = (t >= d) ? s[t - d] : 0;
        __syncthreads();
        s[t] += x;
        __syncthreads();
    }
    if (t < nb) partial[t] = s[t] - v;
}

__global__ __launch_bounds__(256) void add_offsets(int* __restrict__ rowptr,
                                                   const int* __restrict__ partial,
                                                   int n, int E) {
    int i = blockIdx.x * 256 + threadIdx.x;
    if (i < n) rowptr[i] += partial[blockIdx.x];
    if (i == 0) rowptr[n] = E;
}

__global__ __launch_bounds__(256) void fill_csr(const int* __restrict__ row,
                                                const int* __restrict__ col, int E,
                                                const int* __restrict__ rowptr,
                                                int* __restrict__ cursor,
                                                const float* __restrict__ dinv,
                                                float2* __restrict__ csr) {
    int e = blockIdx.x * 256 + threadIdx.x;
    if (e >= E) return;
    int r = row[e], c = col[e];
    int slot = rowptr[c] + atomicAdd(&cursor[c], 1);
    csr[slot] = make_float2(__int_as_float(r), dinv[r]);
}

// C[n,128] = A[n,128] @ W[128,128]; W staged in LDS; 64 rows/block, 256 thr, 32 out/thr
__global__ __launch_bounds__(256) void gemm128(const float* __restrict__ A,
                                               const float* __restrict__ W,
                                               float* __restrict__ C, int n) {
    __shared__ float Ws[128 * 128];
    int tid = threadIdx.x;
    const float4* W4 = (const float4*)W;
    float4* Ws4 = (float4*)Ws;
#pragma unroll
    for (int i = 0; i < 16; i++) Ws4[tid + 256 * i] = W4[tid + 256 * i];
    __syncthreads();

    int r0 = blockIdx.x * 64;
    int tr = tid >> 4;
    int tc = tid & 15;
    float acc[4][8] = {};

    for (int kc = 0; kc < 128; kc += 16) {
        float4 a[4][4];
#pragma unroll
        for (int rr = 0; rr < 4; rr++) {
            int r = r0 + tr + rr * 16;
            if (r < n) {
                const float4* Ar = (const float4*)&A[r * 128 + kc];
                a[rr][0] = Ar[0]; a[rr][1] = Ar[1]; a[rr][2] = Ar[2]; a[rr][3] = Ar[3];
            } else {
                a[rr][0] = a[rr][1] = a[rr][2] = a[rr][3] = make_float4(0, 0, 0, 0);
            }
        }
#pragma unroll
        for (int kk = 0; kk < 16; kk++) {
            float4 w0 = Ws4[((kc + kk) * 128 + tc * 8) >> 2];
            float4 w1 = Ws4[(((kc + kk) * 128 + tc * 8) >> 2) + 1];
#pragma unroll
            for (int rr = 0; rr < 4; rr++) {
                float av = ((const float*)&a[rr][0])[kk];
                acc[rr][0] += av * w0.x; acc[rr][1] += av * w0.y;
                acc[rr][2] += av * w0.z; acc[rr][3] += av * w0.w;
                acc[rr][4] += av * w1.x; acc[rr][5] += av * w1.y;
                acc[rr][6] += av * w1.z; acc[rr][7] += av * w1.w;
            }
        }
    }
#pragma unroll
    for (int rr = 0; rr < 4; rr++) {
        int r = r0 + tr + rr * 16;
        if (r < n) {
            float4* Cp = (float4*)&C[r * 128 + tc * 8];
            Cp[0] = make_float4(acc[rr][0], acc[rr][1], acc[rr][2], acc[rr][3]);
            Cp[1] = make_float4(acc[rr][4], acc[rr][5], acc[rr][6], acc[rr][7]);
        }
    }
}

// one wave per destination node; out = tanh(dinv[c]*(sum + dinv[c]*t[c]) + b)
__global__ __launch_bounds__(256) void aggregate(const float* __restrict__ T,
                                                 const float2* __restrict__ csr,
                                                 const int* __restrict__ rowptr,
                                                 const float* __restrict__ dinv,
                                                 const float* __restrict__ bias,
                                                 float* __restrict__ Out, int n) {
    int node = (int)((blockIdx.x * 256 + threadIdx.x) >> 6);
    int lane = threadIdx.x & 63;
    if (node >= n) return;
    float di = dinv[node];
    float2 t = *(const float2*)&T[node * 128 + lane * 2];
    float ax = t.x * di, ay = t.y * di;
    int beg = rowptr[node], end = rowptr[node + 1];
    for (int e = beg; e < end; e++) {
        float2 sw = csr[e];  // (src, dinv[src]) — wave-uniform address, broadcast
        int src = __float_as_int(sw.x);
        float w = sw.y;
        float2 ts = *(const float2*)&T[src * 128 + lane * 2];
        ax += w * ts.x;
        ay += w * ts.y;
    }
    float bx = bias[lane * 2], by = bias[lane * 2 + 1];
    ax = tanhf(ax * di + bx);
    ay = tanhf(ay * di + by);
    *(float2*)&Out[node * 128 + lane * 2] = make_float2(ax, ay);
}

// layer-2 aggregate fused with the classifier head: logits[node] = tanh(h)·Wc + bc
__global__ __launch_bounds__(256) void aggregate_logits(const float* __restrict__ T,
                                                        const float2* __restrict__ csr,
                                                        const int* __restrict__ rowptr,
                                                        const float* __restrict__ dinv,
                                                        const float* __restrict__ bias,
                                                        const float* __restrict__ Wc,
                                                        const float* __restrict__ bc,
                                                        float* __restrict__ logits, int n) {
    int node = (int)((blockIdx.x * 256 + threadIdx.x) >> 6);
    int lane = threadIdx.x & 63;
    if (node >= n) return;
    float di = dinv[node];
    float2 t = *(const float2*)&T[node * 128 + lane * 2];
    float ax = t.x * di, ay = t.y * di;
    int beg = rowptr[node], end = rowptr[node + 1];
    for (int e = beg; e < end; e++) {
        float2 sw = csr[e];
        int src = __float_as_int(sw.x);
        float w = sw.y;
        float2 ts = *(const float2*)&T[src * 128 + lane * 2];
        ax += w * ts.x;
        ay += w * ts.y;
    }
    float bx = bias[lane * 2], by = bias[lane * 2 + 1];
    ax = tanhf(ax * di + bx);
    ay = tanhf(ay * di + by);
    float2 w = *(const float2*)&Wc[lane * 2];
    float d = ax * w.x + ay * w.y;
#pragma unroll
    for (int off = 32; off; off >>= 1) d += __shfl_xor(d, off);
    if (lane == 0) logits[node] = d + bc[0];
}

// stage 1: 256 blocks produce per-block maxes (deterministic, no atomics)
__global__ __launch_bounds__(256) void maxpart(const float* __restrict__ logits, int n,
                                               float* __restrict__ partialMax) {
    __shared__ float s[256];
    float m = -3.4e38f;
    for (int i = blockIdx.x * 256 + threadIdx.x; i < n; i += 256 * 256)
        m = fmaxf(m, logits[i]);
    s[threadIdx.x] = m;
    __syncthreads();
    for (int d = 128; d; d >>= 1) {
        if (threadIdx.x < d) s[threadIdx.x] = fmaxf(s[threadIdx.x], s[threadIdx.x + d]);
        __syncthreads();
    }
    if (threadIdx.x == 0) partialMax[blockIdx.x] = s[0];
}

// stage 2: each block re-reduces the 256 partial maxes (cheap), then exp + block-sum
__global__ __launch_bounds__(256) void exp_kernel(const float* __restrict__ logits,
                                                  const float* __restrict__ partialMax,
                                                  float* __restrict__ outv,
                                                  float* __restrict__ denom, int n) {
    __shared__ float s[256];
    s[threadIdx.x] = partialMax[threadIdx.x];
    __syncthreads();
    for (int d = 128; d; d >>= 1) {
        if (threadIdx.x < d) s[threadIdx.x] = fmaxf(s[threadIdx.x], s[threadIdx.x + d]);
        __syncthreads();
    }
    float maxv = s[0];
    __syncthreads();
    int i = blockIdx.x * 256 + threadIdx.x;
    float e = 0.0f;
    if (i < n) {
        e = expf(logits[i] - maxv);
        outv[i] = e;
    }
    s[threadIdx.x] = e;
    __syncthreads();
    for (int d = 128; d; d >>= 1) {
        if (threadIdx.x < d) s[threadIdx.x] += s[threadIdx.x + d];
        __syncthreads();
    }
    if (threadIdx.x == 0) atomicAdd(denom, s[0]);
}

__global__ __launch_bounds__(256) void norm_kernel(float* __restrict__ out,
                                                   const float* __restrict__ denom, int n) {
    int i = blockIdx.x * 256 + threadIdx.x;
    if (i < n) out[i] = out[i] / (*denom);
}

extern "C" void kernel_launch(void* const* d_in, const int* in_sizes, int n_in,
                              void* d_out, int out_size, void* d_ws, size_t ws_size,
                              hipStream_t stream) {
    const float* x  = (const float*)d_in[0];
    const int*   ei = (const int*)d_in[1];   // [2,E] int32 (JAX x64 disabled)
    const float* W1 = (const float*)d_in[2];
    const float* b1 = (const float*)d_in[3];
    const float* W2 = (const float*)d_in[4];
    const float* b2 = (const float*)d_in[5];
    const float* Wc = (const float*)d_in[6];
    const float* bc = (const float*)d_in[7];

    int n = in_sizes[0] / 128;
    int E = in_sizes[1] / 2;
    const int* row = ei;
    const int* col = ei + E;

    char* ws = (char*)d_ws;
    size_t off = 0;
    auto alloc = [&](size_t bytes) -> void* {
        void* p = ws + off;
        off += (bytes + 255) & ~(size_t)255;
        return p;
    };
    float*  A      = (float*)alloc((size_t)n * 128 * 4);
    float*  B      = (float*)alloc((size_t)n * 128 * 4);
    float*  dinv   = (float*)alloc((size_t)n * 4);
    int*    deg    = (int*)alloc((size_t)n * 4);
    int*    cursor = (int*)alloc((size_t)n * 4);
    int*    rowptr = (int*)alloc((size_t)(n + 1) * 4);
    int*    partial= (int*)alloc((size_t)((n + 255) / 256) * 4);
    float2* csr    = (float2*)alloc((size_t)E * 8);
    float*  logits = (float*)alloc((size_t)n * 4);
    float*  pmax   = (float*)alloc(256 * 4);
    float*  denom  = (float*)alloc(4);

    int nbN = (n + 255) / 256;
    int nbE = (E + 255) / 256;
    int nbW = (n + 3) / 4;  // 4 waves (nodes) per 256-thread block

    hipMemsetAsync(deg, 0, (size_t)n * 4, stream);
    hipMemsetAsync(cursor, 0, (size_t)n * 4, stream);
    hipMemsetAsync(denom, 0, 4, stream);

    count_deg<<<nbE, 256, 0, stream>>>(col, E, deg);
    compute_dinv<<<nbN, 256, 0, stream>>>(deg, dinv, n);
    scan_blocks<<<nbN, 256, 0, stream>>>(deg, n, rowptr, partial);
    scan_partials<<<1, 512, 0, stream>>>(partial, nbN);
    add_offsets<<<nbN, 256, 0, stream>>>(rowptr, partial, n, E);
    fill_csr<<<nbE, 256, 0, stream>>>(row, col, E, rowptr, cursor, dinv, csr);

    gemm128<<<(n + 63) / 64, 256, 0, stream>>>(x, W1, A, n);
    aggregate<<<nbW, 256, 0, stream>>>(A, csr, rowptr, dinv, b1, B, n);
    gemm128<<<(n + 63) / 64, 256, 0, stream>>>(B, W2, A, n);
    aggregate_logits<<<nbW, 256, 0, stream>>>(A, csr, rowptr, dinv, b2, Wc, bc, logits, n);

    maxpart<<<256, 256, 0, stream>>>(logits, n, pmax);
    exp_kernel<<<nbN, 256, 0, stream>>>(logits, pmax, (float*)d_out, denom, n);
    norm_kernel<<<nbN, 256, 0, stream>>>((float*)d_out, denom, n);
}

// Round 3
// 591.051 us; speedup vs baseline: 3.0321x; 1.1056x over previous
//
#include <hip/hip_runtime.h>

// GCN: 2x (linear -> deg-normalized scatter-add -> bias -> tanh) -> linear(1) -> softmax(N)
// R2: dinv folded into gemm epilogue (csr = int32 src only); wave loads 64 edge
// indices at once + __shfl broadcast (no address-dependent loads in gather loop);
// 2 edges/iter (half-wave each, float4/lane) for 2x MLP; gemm W staged in 2x32KB.

__global__ __launch_bounds__(256) void count_deg(const int* __restrict__ col, int E,
                                                 int* __restrict__ deg) {
    int e = blockIdx.x * 256 + threadIdx.x;
    if (e < E) atomicAdd(&deg[col[e]], 1);
}

// exclusive scan of deg -> rowptr; also computes dinv = 1/sqrt(deg+1)
__global__ __launch_bounds__(256) void scan_blocks(const int* __restrict__ deg, int n,
                                                   int* __restrict__ rowptr,
                                                   int* __restrict__ partial,
                                                   float* __restrict__ dinv) {
    __shared__ int s[256];
    int t = threadIdx.x;
    int i = blockIdx.x * 256 + t;
    int v = (i < n) ? deg[i] : 0;
    if (i < n) dinv[i] = 1.0f / sqrtf((float)(v + 1));  // +1 self loop, always > 0
    s[t] = v;
    __syncthreads();
    for (int d = 1; d < 256; d <<= 1) {
        int x = (t >= d) ? s[t - d] : 0;
        __syncthreads();
        s[t] += x;
        __syncthreads();
    }
    if (i < n) rowptr[i] = s[t] - v;
    if (t == 255) partial[blockIdx.x] = s[255];
}

__global__ void scan_partials(int* partial, int nb) {
    __shared__ int s[512];
    int t = threadIdx.x;
    int v = (t < nb) ? partial[t] : 0;
    s[t] = v;
    __syncthreads();
    for (int d = 1; d < 512; d <<= 1) {
        int x = (t >= d) ? s[t - d] : 0;
        __syncthreads();
        s[t] += x;
        __syncthreads();
    }
    if (t < nb) partial[t] = s[t] - v;
}

__global__ __launch_bounds__(256) void add_offsets(int* __restrict__ rowptr,
                                                   const int* __restrict__ partial,
                                                   int n, int E) {
    int i = blockIdx.x * 256 + threadIdx.x;
    if (i < n) rowptr[i] += partial[blockIdx.x];
    if (i == 0) rowptr[n] = E;
}

__global__ __launch_bounds__(256) void fill_csr(const int* __restrict__ row,
                                                const int* __restrict__ col, int E,
                                                const int* __restrict__ rowptr,
                                                int* __restrict__ cursor,
                                                int* __restrict__ csr) {
    int e = blockIdx.x * 256 + threadIdx.x;
    if (e >= E) return;
    int r = row[e], c = col[e];
    int slot = rowptr[c] + atomicAdd(&cursor[c], 1);
    csr[slot] = r;
}

// C[r,:] = dinv[r] * (A[r,:] @ W); W staged in LDS as 2x 32KB K-halves
__global__ __launch_bounds__(256) void gemm128(const float* __restrict__ A,
                                               const float* __restrict__ W,
                                               const float* __restrict__ dinv,
                                               float* __restrict__ C, int n) {
    __shared__ float Ws[64 * 128];
    int tid = threadIdx.x;
    const float4* W4 = (const float4*)W;
    float4* Ws4 = (float4*)Ws;
    int r0 = blockIdx.x * 64;
    int tr = tid >> 4;
    int tc = tid & 15;
    float acc[4][8] = {};

    for (int kh = 0; kh < 2; kh++) {
        if (kh) __syncthreads();
#pragma unroll
        for (int i = 0; i < 8; i++) Ws4[tid + 256 * i] = W4[kh * 2048 + tid + 256 * i];
        __syncthreads();

        for (int kc = 0; kc < 64; kc += 16) {
            float4 a[4][4];
#pragma unroll
            for (int rr = 0; rr < 4; rr++) {
                int r = r0 + tr + rr * 16;
                if (r < n) {
                    const float4* Ar = (const float4*)&A[(size_t)r * 128 + kh * 64 + kc];
                    a[rr][0] = Ar[0]; a[rr][1] = Ar[1]; a[rr][2] = Ar[2]; a[rr][3] = Ar[3];
                } else {
                    a[rr][0] = a[rr][1] = a[rr][2] = a[rr][3] = make_float4(0, 0, 0, 0);
                }
            }
#pragma unroll
            for (int kk = 0; kk < 16; kk++) {
                float4 w0 = Ws4[((kc + kk) * 128 + tc * 8) >> 2];
                float4 w1 = Ws4[(((kc + kk) * 128 + tc * 8) >> 2) + 1];
#pragma unroll
                for (int rr = 0; rr < 4; rr++) {
                    float av = ((const float*)&a[rr][0])[kk];
                    acc[rr][0] += av * w0.x; acc[rr][1] += av * w0.y;
                    acc[rr][2] += av * w0.z; acc[rr][3] += av * w0.w;
                    acc[rr][4] += av * w1.x; acc[rr][5] += av * w1.y;
                    acc[rr][6] += av * w1.z; acc[rr][7] += av * w1.w;
                }
            }
        }
    }
#pragma unroll
    for (int rr = 0; rr < 4; rr++) {
        int r = r0 + tr + rr * 16;
        if (r < n) {
            float di = dinv[r];
            float4* Cp = (float4*)&C[(size_t)r * 128 + tc * 8];
            Cp[0] = make_float4(acc[rr][0] * di, acc[rr][1] * di, acc[rr][2] * di, acc[rr][3] * di);
            Cp[1] = make_float4(acc[rr][4] * di, acc[rr][5] * di, acc[rr][6] * di, acc[rr][7] * di);
        }
    }
}

// wave per node; T is pre-scaled by dinv. 2 edges/iter: lanes 0-31 edge j
// (float4/lane), lanes 32-63 edge j+1; xor-32 combine at end.
// out = tanh(di*(T[node] + sum_src T[src]) + b)
__global__ __launch_bounds__(256) void aggregate(const float* __restrict__ T,
                                                 const int* __restrict__ csr,
                                                 const int* __restrict__ rowptr,
                                                 const float* __restrict__ dinv,
                                                 const float* __restrict__ bias,
                                                 float* __restrict__ Out, int n) {
    int node = (int)((blockIdx.x * 256 + threadIdx.x) >> 6);
    int lane = threadIdx.x & 63;
    if (node >= n) return;
    int l32 = lane & 31;
    bool lowHalf = lane < 32;

    float4 acc = make_float4(0, 0, 0, 0);
    int beg = rowptr[node], end = rowptr[node + 1];
    int e = beg;
    while (e < end) {
        int take = min(end - e, 64);
        int myidx = (lane < take) ? csr[e + lane] : 0;  // one coalesced load / 64 edges
#pragma unroll 2
        for (int j = 0; j < take; j += 2) {
            int sA = __shfl(myidx, j);
            int sB = (j + 1 < take) ? __shfl(myidx, j + 1) : sA;
            int src = lowHalf ? sA : sB;
            float4 ts = *(const float4*)&T[(size_t)src * 128 + l32 * 4];
            if (lowHalf || (j + 1 < take)) {
                acc.x += ts.x; acc.y += ts.y; acc.z += ts.z; acc.w += ts.w;
            }
        }
        e += take;
    }
    // combine halves (both end with full sum, duplicated)
    acc.x += __shfl_xor(acc.x, 32);
    acc.y += __shfl_xor(acc.y, 32);
    acc.z += __shfl_xor(acc.z, 32);
    acc.w += __shfl_xor(acc.w, 32);

    float di = dinv[node];
    float4 self = *(const float4*)&T[(size_t)node * 128 + l32 * 4];
    float4 b = *(const float4*)&bias[l32 * 4];
    float4 o;
    o.x = tanhf((acc.x + self.x) * di + b.x);
    o.y = tanhf((acc.y + self.y) * di + b.y);
    o.z = tanhf((acc.z + self.z) * di + b.z);
    o.w = tanhf((acc.w + self.w) * di + b.w);
    if (lowHalf) *(float4*)&Out[(size_t)node * 128 + l32 * 4] = o;
}

// same as aggregate, fused with classifier head: logits[node] = tanh(h)·Wc + bc
__global__ __launch_bounds__(256) void aggregate_logits(const float* __restrict__ T,
                                                        const int* __restrict__ csr,
                                                        const int* __restrict__ rowptr,
                                                        const float* __restrict__ dinv,
                                                        const float* __restrict__ bias,
                                                        const float* __restrict__ Wc,
                                                        const float* __restrict__ bc,
                                                        float* __restrict__ logits, int n) {
    int node = (int)((blockIdx.x * 256 + threadIdx.x) >> 6);
    int lane = threadIdx.x & 63;
    if (node >= n) return;
    int l32 = lane & 31;
    bool lowHalf = lane < 32;

    float4 acc = make_float4(0, 0, 0, 0);
    int beg = rowptr[node], end = rowptr[node + 1];
    int e = beg;
    while (e < end) {
        int take = min(end - e, 64);
        int myidx = (lane < take) ? csr[e + lane] : 0;
#pragma unroll 2
        for (int j = 0; j < take; j += 2) {
            int sA = __shfl(myidx, j);
            int sB = (j + 1 < take) ? __shfl(myidx, j + 1) : sA;
            int src = lowHalf ? sA : sB;
            float4 ts = *(const float4*)&T[(size_t)src * 128 + l32 * 4];
            if (lowHalf || (j + 1 < take)) {
                acc.x += ts.x; acc.y += ts.y; acc.z += ts.z; acc.w += ts.w;
            }
        }
        e += take;
    }
    acc.x += __shfl_xor(acc.x, 32);
    acc.y += __shfl_xor(acc.y, 32);
    acc.z += __shfl_xor(acc.z, 32);
    acc.w += __shfl_xor(acc.w, 32);

    float di = dinv[node];
    float4 self = *(const float4*)&T[(size_t)node * 128 + l32 * 4];
    float4 b = *(const float4*)&bias[l32 * 4];
    float4 w = *(const float4*)&Wc[l32 * 4];
    float d = tanhf((acc.x + self.x) * di + b.x) * w.x
            + tanhf((acc.y + self.y) * di + b.y) * w.y
            + tanhf((acc.z + self.z) * di + b.z) * w.z
            + tanhf((acc.w + self.w) * di + b.w) * w.w;
    // reduce within low 32 lanes (they cover all 128 dims)
#pragma unroll
    for (int off = 16; off; off >>= 1) d += __shfl_xor(d, off);
    if (lane == 0) logits[node] = d + bc[0];
}

// stage 1: 256 blocks produce per-block maxes; block 0 also zeroes denom
__global__ __launch_bounds__(256) void maxpart(const float* __restrict__ logits, int n,
                                               float* __restrict__ partialMax,
                                               float* __restrict__ denom) {
    if (blockIdx.x == 0 && threadIdx.x == 0) *denom = 0.0f;
    __shared__ float s[256];
    float m = -3.4e38f;
    for (int i = blockIdx.x * 256 + threadIdx.x; i < n; i += 256 * 256)
        m = fmaxf(m, logits[i]);
    s[threadIdx.x] = m;
    __syncthreads();
    for (int d = 128; d; d >>= 1) {
        if (threadIdx.x < d) s[threadIdx.x] = fmaxf(s[threadIdx.x], s[threadIdx.x + d]);
        __syncthreads();
    }
    if (threadIdx.x == 0) partialMax[blockIdx.x] = s[0];
}

__global__ __launch_bounds__(256) void exp_kernel(const float* __restrict__ logits,
                                                  const float* __restrict__ partialMax,
                                                  float* __restrict__ outv,
                                                  float* __restrict__ denom, int n) {
    __shared__ float s[256];
    s[threadIdx.x] = partialMax[threadIdx.x];
    __syncthreads();
    for (int d = 128; d; d >>= 1) {
        if (threadIdx.x < d) s[threadIdx.x] = fmaxf(s[threadIdx.x], s[threadIdx.x + d]);
        __syncthreads();
    }
    float maxv = s[0];
    __syncthreads();
    int i = blockIdx.x * 256 + threadIdx.x;
    float e = 0.0f;
    if (i < n) {
        e = expf(logits[i] - maxv);
        outv[i] = e;
    }
    s[threadIdx.x] = e;
    __syncthreads();
    for (int d = 128; d; d >>= 1) {
        if (threadIdx.x < d) s[threadIdx.x] += s[threadIdx.x + d];
        __syncthreads();
    }
    if (threadIdx.x == 0) atomicAdd(denom, s[0]);
}

__global__ __launch_bounds__(256) void norm_kernel(float* __restrict__ out,
                                                   const float* __restrict__ denom, int n) {
    int i = blockIdx.x * 256 + threadIdx.x;
    if (i < n) out[i] = out[i] / (*denom);
}

extern "C" void kernel_launch(void* const* d_in, const int* in_sizes, int n_in,
                              void* d_out, int out_size, void* d_ws, size_t ws_size,
                              hipStream_t stream) {
    const float* x  = (const float*)d_in[0];
    const int*   ei = (const int*)d_in[1];   // [2,E] int32 (JAX x64 disabled)
    const float* W1 = (const float*)d_in[2];
    const float* b1 = (const float*)d_in[3];
    const float* W2 = (const float*)d_in[4];
    const float* b2 = (const float*)d_in[5];
    const float* Wc = (const float*)d_in[6];
    const float* bc = (const float*)d_in[7];

    int n = in_sizes[0] / 128;
    int E = in_sizes[1] / 2;
    const int* row = ei;
    const int* col = ei + E;

    char* ws = (char*)d_ws;
    size_t off = 0;
    auto alloc = [&](size_t bytes) -> void* {
        void* p = ws + off;
        off += (bytes + 255) & ~(size_t)255;
        return p;
    };
    float*  A      = (float*)alloc((size_t)n * 128 * 4);
    float*  B      = (float*)alloc((size_t)n * 128 * 4);
    float*  dinv   = (float*)alloc((size_t)n * 4);
    int*    deg    = (int*)alloc((size_t)n * 4);
    int*    cursor = (int*)alloc((size_t)n * 4);   // adjacent to deg: one memset spans both
    int*    rowptr = (int*)alloc((size_t)(n + 1) * 4);
    int*    partial= (int*)alloc((size_t)((n + 255) / 256) * 4);
    int*    csr    = (int*)alloc((size_t)E * 4);
    float*  logits = (float*)alloc((size_t)n * 4);
    float*  pmax   = (float*)alloc(256 * 4);
    float*  denom  = (float*)alloc(4);

    int nbN = (n + 255) / 256;
    int nbE = (E + 255) / 256;
    int nbW = (n + 3) / 4;  // 4 waves (nodes) per 256-thread block

    size_t zspan = (size_t)((char*)cursor - (char*)deg) + (size_t)n * 4;
    hipMemsetAsync(deg, 0, zspan, stream);

    count_deg<<<nbE, 256, 0, stream>>>(col, E, deg);
    scan_blocks<<<nbN, 256, 0, stream>>>(deg, n, rowptr, partial, dinv);
    scan_partials<<<1, 512, 0, stream>>>(partial, nbN);
    add_offsets<<<nbN, 256, 0, stream>>>(rowptr, partial, n, E);
    fill_csr<<<nbE, 256, 0, stream>>>(row, col, E, rowptr, cursor, csr);

    gemm128<<<(n + 63) / 64, 256, 0, stream>>>(x, W1, dinv, A, n);
    aggregate<<<nbW, 256, 0, stream>>>(A, csr, rowptr, dinv, b1, B, n);
    gemm128<<<(n + 63) / 64, 256, 0, stream>>>(B, W2, dinv, A, n);
    aggregate_logits<<<nbW, 256, 0, stream>>>(A, csr, rowptr, dinv, b2, Wc, bc, logits, n);

    maxpart<<<256, 256, 0, stream>>>(logits, n, pmax, denom);
    exp_kernel<<<nbN, 256, 0, stream>>>(logits, pmax, (float*)d_out, denom, n);
    norm_kernel<<<nbN, 256, 0, stream>>>((float*)d_out, denom, n);
}

// Round 4
// 471.951 us; speedup vs baseline: 3.7972x; 1.2524x over previous
//
#include <hip/hip_runtime.h>
#include <hip/hip_fp16.h>

// GCN: 2x (linear -> deg-normalized scatter-add -> bias -> tanh) -> linear(1) -> softmax(N)
// R3: intermediate features stored fp16 (compute fp32) -> halves gather bytes.
// Aggregate: 4 edges/iter, 16 lanes/edge (ushort8/lane), shfl_xor group combine.

__device__ inline void h8_to_f(uint4 v, float* f) {
    float2 p;
    p = __half22float2(__builtin_bit_cast(__half2, v.x)); f[0] = p.x; f[1] = p.y;
    p = __half22float2(__builtin_bit_cast(__half2, v.y)); f[2] = p.x; f[3] = p.y;
    p = __half22float2(__builtin_bit_cast(__half2, v.z)); f[4] = p.x; f[5] = p.y;
    p = __half22float2(__builtin_bit_cast(__half2, v.w)); f[6] = p.x; f[7] = p.y;
}

__device__ inline uint4 f_to_h8(const float* f) {
    uint4 v;
    v.x = __builtin_bit_cast(unsigned int, __floats2half2_rn(f[0], f[1]));
    v.y = __builtin_bit_cast(unsigned int, __floats2half2_rn(f[2], f[3]));
    v.z = __builtin_bit_cast(unsigned int, __floats2half2_rn(f[4], f[5]));
    v.w = __builtin_bit_cast(unsigned int, __floats2half2_rn(f[6], f[7]));
    return v;
}

__global__ __launch_bounds__(256) void count_deg(const int* __restrict__ col, int E,
                                                 int* __restrict__ deg) {
    int e = blockIdx.x * 256 + threadIdx.x;
    if (e < E) atomicAdd(&deg[col[e]], 1);
}

// exclusive scan of deg -> rowptr; also computes dinv = 1/sqrt(deg+1)
__global__ __launch_bounds__(256) void scan_blocks(const int* __restrict__ deg, int n,
                                                   int* __restrict__ rowptr,
                                                   int* __restrict__ partial,
                                                   float* __restrict__ dinv) {
    __shared__ int s[256];
    int t = threadIdx.x;
    int i = blockIdx.x * 256 + t;
    int v = (i < n) ? deg[i] : 0;
    if (i < n) dinv[i] = 1.0f / sqrtf((float)(v + 1));
    s[t] = v;
    __syncthreads();
    for (int d = 1; d < 256; d <<= 1) {
        int x = (t >= d) ? s[t - d] : 0;
        __syncthreads();
        s[t] += x;
        __syncthreads();
    }
    if (i < n) rowptr[i] = s[t] - v;
    if (t == 255) partial[blockIdx.x] = s[255];
}

__global__ void scan_partials(int* partial, int nb) {
    __shared__ int s[512];
    int t = threadIdx.x;
    int v = (t < nb) ? partial[t] : 0;
    s[t] = v;
    __syncthreads();
    for (int d = 1; d < 512; d <<= 1) {
        int x = (t >= d) ? s[t - d] : 0;
        __syncthreads();
        s[t] += x;
        __syncthreads();
    }
    if (t < nb) partial[t] = s[t] - v;
}

__global__ __launch_bounds__(256) void add_offsets(int* __restrict__ rowptr,
                                                   const int* __restrict__ partial,
                                                   int n, int E) {
    int i = blockIdx.x * 256 + threadIdx.x;
    if (i < n) rowptr[i] += partial[blockIdx.x];
    if (i == 0) rowptr[n] = E;
}

__global__ __launch_bounds__(256) void fill_csr(const int* __restrict__ row,
                                                const int* __restrict__ col, int E,
                                                const int* __restrict__ rowptr,
                                                int* __restrict__ cursor,
                                                int* __restrict__ csr) {
    int e = blockIdx.x * 256 + threadIdx.x;
    if (e >= E) return;
    int r = row[e], c = col[e];
    int slot = rowptr[c] + atomicAdd(&cursor[c], 1);
    csr[slot] = r;
}

// C[r,:] = fp16( dinv[r] * (A[r,:] @ W) ); A fp32 or fp16; W staged 2x32KB in LDS
template <bool HALF_IN>
__global__ __launch_bounds__(256) void gemm128(const void* __restrict__ Ap,
                                               const float* __restrict__ W,
                                               const float* __restrict__ dinv,
                                               uint4* __restrict__ C, int n) {
    __shared__ float Ws[64 * 128];
    int tid = threadIdx.x;
    const float4* W4 = (const float4*)W;
    float4* Ws4 = (float4*)Ws;
    int r0 = blockIdx.x * 64;
    int tr = tid >> 4;
    int tc = tid & 15;
    float acc[4][8] = {};

    for (int kh = 0; kh < 2; kh++) {
        if (kh) __syncthreads();
#pragma unroll
        for (int i = 0; i < 8; i++) Ws4[tid + 256 * i] = W4[kh * 2048 + tid + 256 * i];
        __syncthreads();

        for (int kc = 0; kc < 64; kc += 16) {
            float a[4][16];
#pragma unroll
            for (int rr = 0; rr < 4; rr++) {
                int r = r0 + tr + rr * 16;
                if (r < n) {
                    if constexpr (HALF_IN) {
                        const uint4* Ar = (const uint4*)Ap + (size_t)r * 16 + (kh * 64 + kc) / 8;
                        h8_to_f(Ar[0], &a[rr][0]);
                        h8_to_f(Ar[1], &a[rr][8]);
                    } else {
                        const float4* Ar = (const float4*)((const float*)Ap + (size_t)r * 128 + kh * 64 + kc);
#pragma unroll
                        for (int q = 0; q < 4; q++) {
                            float4 v = Ar[q];
                            a[rr][q * 4 + 0] = v.x; a[rr][q * 4 + 1] = v.y;
                            a[rr][q * 4 + 2] = v.z; a[rr][q * 4 + 3] = v.w;
                        }
                    }
                } else {
#pragma unroll
                    for (int q = 0; q < 16; q++) a[rr][q] = 0.0f;
                }
            }
#pragma unroll
            for (int kk = 0; kk < 16; kk++) {
                float4 w0 = Ws4[((kc + kk) * 128 + tc * 8) >> 2];
                float4 w1 = Ws4[(((kc + kk) * 128 + tc * 8) >> 2) + 1];
#pragma unroll
                for (int rr = 0; rr < 4; rr++) {
                    float av = a[rr][kk];
                    acc[rr][0] += av * w0.x; acc[rr][1] += av * w0.y;
                    acc[rr][2] += av * w0.z; acc[rr][3] += av * w0.w;
                    acc[rr][4] += av * w1.x; acc[rr][5] += av * w1.y;
                    acc[rr][6] += av * w1.z; acc[rr][7] += av * w1.w;
                }
            }
        }
    }
#pragma unroll
    for (int rr = 0; rr < 4; rr++) {
        int r = r0 + tr + rr * 16;
        if (r < n) {
            float di = dinv[r];
            float o[8];
#pragma unroll
            for (int q = 0; q < 8; q++) o[q] = acc[rr][q] * di;
            C[(size_t)r * 16 + tc] = f_to_h8(o);
        }
    }
}

// wave per node; T fp16 pre-scaled by dinv. 4 edges/iter: group g (16 lanes) handles
// edge j+g, each lane one ushort8 (8 dims). Combine groups via shfl_xor(16,32).
// out = fp16( tanh(di*(T[node] + sum_src T[src]) + b) )
__global__ __launch_bounds__(256) void aggregate(const uint4* __restrict__ T,
                                                 const int* __restrict__ csr,
                                                 const int* __restrict__ rowptr,
                                                 const float* __restrict__ dinv,
                                                 const float* __restrict__ bias,
                                                 uint4* __restrict__ Out, int n) {
    int node = (int)((blockIdx.x * 256 + threadIdx.x) >> 6);
    int lane = threadIdx.x & 63;
    if (node >= n) return;
    int grp = lane >> 4, m = lane & 15;

    float acc[8] = {};
    int beg = rowptr[node], end = rowptr[node + 1];
    int e = beg;
    while (e < end) {
        int take = min(end - e, 64);
        int myidx = (lane < take) ? csr[e + lane] : 0;  // one coalesced load / 64 edges
#pragma unroll 4
        for (int j = 0; j < take; j += 4) {
            int src = __shfl(myidx, j + grp);
            if (j + grp < take) {
                uint4 v = T[(size_t)src * 16 + m];
                float f[8];
                h8_to_f(v, f);
#pragma unroll
                for (int q = 0; q < 8; q++) acc[q] += f[q];
            }
        }
        e += take;
    }
#pragma unroll
    for (int q = 0; q < 8; q++) {
        acc[q] += __shfl_xor(acc[q], 16);
        acc[q] += __shfl_xor(acc[q], 32);
    }

    float di = dinv[node];
    float self[8];
    h8_to_f(T[(size_t)node * 16 + m], self);
    const float4* bp = (const float4*)&bias[m * 8];
    float4 b0 = bp[0], b1 = bp[1];
    float bb[8] = {b0.x, b0.y, b0.z, b0.w, b1.x, b1.y, b1.z, b1.w};
    float o[8];
#pragma unroll
    for (int q = 0; q < 8; q++) o[q] = tanhf((acc[q] + self[q]) * di + bb[q]);
    if (grp == 0) Out[(size_t)node * 16 + m] = f_to_h8(o);
}

// same, fused with classifier head: logits[node] = tanh(h)·Wc + bc  (fp32 out)
__global__ __launch_bounds__(256) void aggregate_logits(const uint4* __restrict__ T,
                                                        const int* __restrict__ csr,
                                                        const int* __restrict__ rowptr,
                                                        const float* __restrict__ dinv,
                                                        const float* __restrict__ bias,
                                                        const float* __restrict__ Wc,
                                                        const float* __restrict__ bc,
                                                        float* __restrict__ logits, int n) {
    int node = (int)((blockIdx.x * 256 + threadIdx.x) >> 6);
    int lane = threadIdx.x & 63;
    if (node >= n) return;
    int grp = lane >> 4, m = lane & 15;

    float acc[8] = {};
    int beg = rowptr[node], end = rowptr[node + 1];
    int e = beg;
    while (e < end) {
        int take = min(end - e, 64);
        int myidx = (lane < take) ? csr[e + lane] : 0;
#pragma unroll 4
        for (int j = 0; j < take; j += 4) {
            int src = __shfl(myidx, j + grp);
            if (j + grp < take) {
                uint4 v = T[(size_t)src * 16 + m];
                float f[8];
                h8_to_f(v, f);
#pragma unroll
                for (int q = 0; q < 8; q++) acc[q] += f[q];
            }
        }
        e += take;
    }
#pragma unroll
    for (int q = 0; q < 8; q++) {
        acc[q] += __shfl_xor(acc[q], 16);
        acc[q] += __shfl_xor(acc[q], 32);
    }

    float di = dinv[node];
    float self[8];
    h8_to_f(T[(size_t)node * 16 + m], self);
    const float4* bp = (const float4*)&bias[m * 8];
    float4 b0 = bp[0], b1 = bp[1];
    float bb[8] = {b0.x, b0.y, b0.z, b0.w, b1.x, b1.y, b1.z, b1.w};
    const float4* wp = (const float4*)&Wc[m * 8];
    float4 w0 = wp[0], w1 = wp[1];
    float ww[8] = {w0.x, w0.y, w0.z, w0.w, w1.x, w1.y, w1.z, w1.w};
    float d = 0.0f;
#pragma unroll
    for (int q = 0; q < 8; q++) d += tanhf((acc[q] + self[q]) * di + bb[q]) * ww[q];
    // reduce within the 16-lane group (groups hold identical values)
#pragma unroll
    for (int off = 8; off; off >>= 1) d += __shfl_xor(d, off);
    if (lane == 0) logits[node] = d + bc[0];
}

// stage 1: 256 blocks produce per-block maxes; block 0 also zeroes denom
__global__ __launch_bounds__(256) void maxpart(const float* __restrict__ logits, int n,
                                               float* __restrict__ partialMax,
                                               float* __restrict__ denom) {
    if (blockIdx.x == 0 && threadIdx.x == 0) *denom = 0.0f;
    __shared__ float s[256];
    float m = -3.4e38f;
    for (int i = blockIdx.x * 256 + threadIdx.x; i < n; i += 256 * 256)
        m = fmaxf(m, logits[i]);
    s[threadIdx.x] = m;
    __syncthreads();
    for (int d = 128; d; d >>= 1) {
        if (threadIdx.x < d) s[threadIdx.x] = fmaxf(s[threadIdx.x], s[threadIdx.x + d]);
        __syncthreads();
    }
    if (threadIdx.x == 0) partialMax[blockIdx.x] = s[0];
}

__global__ __launch_bounds__(256) void exp_kernel(const float* __restrict__ logits,
                                                  const float* __restrict__ partialMax,
                                                  float* __restrict__ outv,
                                                  float* __restrict__ denom, int n) {
    __shared__ float s[256];
    s[threadIdx.x] = partialMax[threadIdx.x];
    __syncthreads();
    for (int d = 128; d; d >>= 1) {
        if (threadIdx.x < d) s[threadIdx.x] = fmaxf(s[threadIdx.x], s[threadIdx.x + d]);
        __syncthreads();
    }
    float maxv = s[0];
    __syncthreads();
    int i = blockIdx.x * 256 + threadIdx.x;
    float e = 0.0f;
    if (i < n) {
        e = expf(logits[i] - maxv);
        outv[i] = e;
    }
    s[threadIdx.x] = e;
    __syncthreads();
    for (int d = 128; d; d >>= 1) {
        if (threadIdx.x < d) s[threadIdx.x] += s[threadIdx.x + d];
        __syncthreads();
    }
    if (threadIdx.x == 0) atomicAdd(denom, s[0]);
}

__global__ __launch_bounds__(256) void norm_kernel(float* __restrict__ out,
                                                   const float* __restrict__ denom, int n) {
    int i = blockIdx.x * 256 + threadIdx.x;
    if (i < n) out[i] = out[i] / (*denom);
}

extern "C" void kernel_launch(void* const* d_in, const int* in_sizes, int n_in,
                              void* d_out, int out_size, void* d_ws, size_t ws_size,
                              hipStream_t stream) {
    const float* x  = (const float*)d_in[0];
    const int*   ei = (const int*)d_in[1];   // [2,E] int32 (JAX x64 disabled)
    const float* W1 = (const float*)d_in[2];
    const float* b1 = (const float*)d_in[3];
    const float* W2 = (const float*)d_in[4];
    const float* b2 = (const float*)d_in[5];
    const float* Wc = (const float*)d_in[6];
    const float* bc = (const float*)d_in[7];

    int n = in_sizes[0] / 128;
    int E = in_sizes[1] / 2;
    const int* row = ei;
    const int* col = ei + E;

    char* ws = (char*)d_ws;
    size_t off = 0;
    auto alloc = [&](size_t bytes) -> void* {
        void* p = ws + off;
        off += (bytes + 255) & ~(size_t)255;
        return p;
    };
    uint4*  A      = (uint4*)alloc((size_t)n * 128 * 2);   // fp16 features
    uint4*  B      = (uint4*)alloc((size_t)n * 128 * 2);   // fp16 features
    float*  dinv   = (float*)alloc((size_t)n * 4);
    int*    deg    = (int*)alloc((size_t)n * 4);
    int*    cursor = (int*)alloc((size_t)n * 4);   // adjacent to deg: one memset spans both
    int*    rowptr = (int*)alloc((size_t)(n + 1) * 4);
    int*    partial= (int*)alloc((size_t)((n + 255) / 256) * 4);
    int*    csr    = (int*)alloc((size_t)E * 4);
    float*  logits = (float*)alloc((size_t)n * 4);
    float*  pmax   = (float*)alloc(256 * 4);
    float*  denom  = (float*)alloc(4);

    int nbN = (n + 255) / 256;
    int nbE = (E + 255) / 256;
    int nbW = (n + 3) / 4;  // 4 waves (nodes) per 256-thread block

    size_t zspan = (size_t)((char*)cursor - (char*)deg) + (size_t)n * 4;
    hipMemsetAsync(deg, 0, zspan, stream);

    count_deg<<<nbE, 256, 0, stream>>>(col, E, deg);
    scan_blocks<<<nbN, 256, 0, stream>>>(deg, n, rowptr, partial, dinv);
    scan_partials<<<1, 512, 0, stream>>>(partial, nbN);
    add_offsets<<<nbN, 256, 0, stream>>>(rowptr, partial, n, E);
    fill_csr<<<nbE, 256, 0, stream>>>(row, col, E, rowptr, cursor, csr);

    gemm128<false><<<(n + 63) / 64, 256, 0, stream>>>(x, W1, dinv, A, n);
    aggregate<<<nbW, 256, 0, stream>>>(A, csr, rowptr, dinv, b1, B, n);
    gemm128<true><<<(n + 63) / 64, 256, 0, stream>>>(B, W2, dinv, A, n);
    aggregate_logits<<<nbW, 256, 0, stream>>>(A, csr, rowptr, dinv, b2, Wc, bc, logits, n);

    maxpart<<<256, 256, 0, stream>>>(logits, n, pmax, denom);
    exp_kernel<<<nbN, 256, 0, stream>>>(logits, pmax, (float*)d_out, denom, n);
    norm_kernel<<<nbN, 256, 0, stream>>>((float*)d_out, denom, n);
}

// Round 5
// 344.673 us; speedup vs baseline: 5.1995x; 1.3693x over previous
//
#include <hip/hip_runtime.h>
#include <hip/hip_fp16.h>

// GCN: 2x (linear -> deg-normalized scatter-add -> bias -> tanh) -> linear(1) -> softmax(N)
// R4: CSR build via 2-level bucket counting-sort (kills fill_csr's 17x write
// amplification + count_deg's random atomics). fp16 features, fp32 compute.

#define BSHIFT 9
#define BSPAN  512            // 1 << BSHIFT
#define PCHUNK 4096           // edges per partition block
#define LCAP   12288          // per-bucket LDS staging capacity (mean 8192 + 45 sigma)

__device__ inline void h8_to_f(uint4 v, float* f) {
    float2 p;
    p = __half22float2(__builtin_bit_cast(__half2, v.x)); f[0] = p.x; f[1] = p.y;
    p = __half22float2(__builtin_bit_cast(__half2, v.y)); f[2] = p.x; f[3] = p.y;
    p = __half22float2(__builtin_bit_cast(__half2, v.z)); f[4] = p.x; f[5] = p.y;
    p = __half22float2(__builtin_bit_cast(__half2, v.w)); f[6] = p.x; f[7] = p.y;
}

__device__ inline uint4 f_to_h8(const float* f) {
    uint4 v;
    v.x = __builtin_bit_cast(unsigned int, __floats2half2_rn(f[0], f[1]));
    v.y = __builtin_bit_cast(unsigned int, __floats2half2_rn(f[2], f[3]));
    v.z = __builtin_bit_cast(unsigned int, __floats2half2_rn(f[4], f[5]));
    v.w = __builtin_bit_cast(unsigned int, __floats2half2_rn(f[6], f[7]));
    return v;
}

// ---- CSR build, pass A: per-bucket edge histogram (bucket = dst >> BSHIFT) ----
__global__ __launch_bounds__(256) void hist_buckets(const int* __restrict__ col, int E,
                                                    int* __restrict__ bucketCnt) {
    __shared__ int h[256];
    h[threadIdx.x] = 0;
    __syncthreads();
    for (int e = blockIdx.x * 256 + threadIdx.x; e < E; e += gridDim.x * 256)
        atomicAdd(&h[col[e] >> BSHIFT], 1);
    __syncthreads();
    int v = h[threadIdx.x];
    if (v) atomicAdd(&bucketCnt[threadIdx.x], v);
}

// ---- pass B: scan bucket counts -> bucketPtr (+cursor copy for pass C) ----
__global__ void scan_buckets(const int* __restrict__ cnt, int* __restrict__ bucketPtr,
                             int* __restrict__ cursor, int NB, int E) {
    __shared__ int s[256];
    int t = threadIdx.x;
    int v = (t < NB) ? cnt[t] : 0;
    s[t] = v;
    __syncthreads();
    for (int d = 1; d < 256; d <<= 1) {
        int x = (t >= d) ? s[t - d] : 0;
        __syncthreads();
        s[t] += x;
        __syncthreads();
    }
    if (t < NB) {
        int p = s[t] - v;
        bucketPtr[t] = p;
        cursor[t] = p;
    }
    if (t == 0) bucketPtr[NB] = E;
}

// ---- pass C: partition edges into bucket-contiguous (c,r) pairs, LDS-staged
// so global writes are line-coalesced runs ----
__global__ __launch_bounds__(256) void partition_edges(const int* __restrict__ row,
                                                       const int* __restrict__ col, int E,
                                                       int* __restrict__ cursor,
                                                       uint2* __restrict__ pairs) {
    __shared__ int hist[256], sscan[256], gdelta[256], hcur[256];
    __shared__ uint2 stage[PCHUNK];
    int t = threadIdx.x;
    int base = blockIdx.x * PCHUNK;
    int cnt = min(PCHUNK, E - base);
    hist[t] = 0;
    __syncthreads();
    uint2 v[16];
    int b_[16];
#pragma unroll
    for (int k = 0; k < 16; k++) {
        int idx = t + k * 256;
        if (idx < cnt) {
            int c = col[base + idx], r = row[base + idx];
            v[k] = make_uint2((unsigned)c, (unsigned)r);
            b_[k] = c >> BSHIFT;
            atomicAdd(&hist[b_[k]], 1);
        } else b_[k] = -1;
    }
    __syncthreads();
    int hv = hist[t];
    sscan[t] = hv;
    __syncthreads();
    for (int d = 1; d < 256; d <<= 1) {
        int x = (t >= d) ? sscan[t - d] : 0;
        __syncthreads();
        sscan[t] += x;
        __syncthreads();
    }
    int excl = sscan[t] - hv;
    if (hv > 0) {
        int g = atomicAdd(&cursor[t], hv);
        gdelta[t] = g - excl;
    }
    hcur[t] = excl;
    __syncthreads();
#pragma unroll
    for (int k = 0; k < 16; k++) {
        if (b_[k] >= 0) {
            int slot = atomicAdd(&hcur[b_[k]], 1);
            stage[slot] = v[k];
        }
    }
    __syncthreads();
    for (int i = t; i < cnt; i += 256) {
        uint2 p = stage[i];
        pairs[gdelta[p.x >> BSHIFT] + i] = p;   // consecutive i -> consecutive dest per run
    }
}

// ---- pass D: per bucket (512 dst nodes): local hist -> scan -> LDS scatter ->
// coalesced csr write; emits rowptr and dinv (deg from hist) ----
__global__ __launch_bounds__(256) void build_bucket_csr(const uint2* __restrict__ pairs,
                                                        const int* __restrict__ bucketPtr,
                                                        int* __restrict__ rowptr,
                                                        float* __restrict__ dinv,
                                                        int* __restrict__ csr,
                                                        int n, int NB, int E) {
    __shared__ int hist[BSPAN];
    __shared__ int lptr[BSPAN];
    __shared__ int s[256];
    __shared__ int srcStage[LCAP];
    int b = blockIdx.x, t = threadIdx.x;
    int base = bucketPtr[b], cnt = bucketPtr[b + 1] - base;
    int node0 = b << BSHIFT;
    int nn = min(BSPAN, n - node0);
    hist[t] = 0; hist[t + 256] = 0;
    __syncthreads();
    for (int i = t; i < cnt; i += 256)
        atomicAdd(&hist[pairs[base + i].x & (BSPAN - 1)], 1);
    __syncthreads();
    int a0 = hist[2 * t], a1 = hist[2 * t + 1];
    int sum = a0 + a1;
    s[t] = sum;
    __syncthreads();
    for (int d = 1; d < 256; d <<= 1) {
        int x = (t >= d) ? s[t - d] : 0;
        __syncthreads();
        s[t] += x;
        __syncthreads();
    }
    int excl = s[t] - sum;
    lptr[2 * t] = excl;
    lptr[2 * t + 1] = excl + a0;
    __syncthreads();
    for (int lc = t; lc < nn; lc += 256) {
        rowptr[node0 + lc] = base + lptr[lc];
        dinv[node0 + lc] = rsqrtf((float)(hist[lc] + 1));  // +1 self loop
    }
    if (b == NB - 1 && t == 0) rowptr[n] = E;
    __syncthreads();
    hist[t] = 0; hist[t + 256] = 0;   // reuse as cursors
    __syncthreads();
    bool inLds = (cnt <= LCAP);
    for (int i = t; i < cnt; i += 256) {
        uint2 p = pairs[base + i];
        int lc = p.x & (BSPAN - 1);
        int rank = atomicAdd(&hist[lc], 1);
        int slot = lptr[lc] + rank;
        if (inLds) srcStage[slot] = (int)p.y;
        else csr[base + slot] = (int)p.y;   // overflow fallback (correct, slower)
    }
    __syncthreads();
    if (inLds)
        for (int i = t; i < cnt; i += 256) csr[base + i] = srcStage[i];
}

// ---- C[r,:] = fp16( dinv[r] * (A[r,:] @ W) ); W staged 2x32KB in LDS ----
template <bool HALF_IN>
__global__ __launch_bounds__(256) void gemm128(const void* __restrict__ Ap,
                                               const float* __restrict__ W,
                                               const float* __restrict__ dinv,
                                               uint4* __restrict__ C, int n) {
    __shared__ float Ws[64 * 128];
    int tid = threadIdx.x;
    const float4* W4 = (const float4*)W;
    float4* Ws4 = (float4*)Ws;
    int r0 = blockIdx.x * 64;
    int tr = tid >> 4;
    int tc = tid & 15;
    float acc[4][8] = {};

    for (int kh = 0; kh < 2; kh++) {
        if (kh) __syncthreads();
#pragma unroll
        for (int i = 0; i < 8; i++) Ws4[tid + 256 * i] = W4[kh * 2048 + tid + 256 * i];
        __syncthreads();

        for (int kc = 0; kc < 64; kc += 16) {
            float a[4][16];
#pragma unroll
            for (int rr = 0; rr < 4; rr++) {
                int r = r0 + tr + rr * 16;
                if (r < n) {
                    if constexpr (HALF_IN) {
                        const uint4* Ar = (const uint4*)Ap + (size_t)r * 16 + (kh * 64 + kc) / 8;
                        h8_to_f(Ar[0], &a[rr][0]);
                        h8_to_f(Ar[1], &a[rr][8]);
                    } else {
                        const float4* Ar = (const float4*)((const float*)Ap + (size_t)r * 128 + kh * 64 + kc);
#pragma unroll
                        for (int q = 0; q < 4; q++) {
                            float4 vv = Ar[q];
                            a[rr][q * 4 + 0] = vv.x; a[rr][q * 4 + 1] = vv.y;
                            a[rr][q * 4 + 2] = vv.z; a[rr][q * 4 + 3] = vv.w;
                        }
                    }
                } else {
#pragma unroll
                    for (int q = 0; q < 16; q++) a[rr][q] = 0.0f;
                }
            }
#pragma unroll
            for (int kk = 0; kk < 16; kk++) {
                float4 w0 = Ws4[((kc + kk) * 128 + tc * 8) >> 2];
                float4 w1 = Ws4[(((kc + kk) * 128 + tc * 8) >> 2) + 1];
#pragma unroll
                for (int rr = 0; rr < 4; rr++) {
                    float av = a[rr][kk];
                    acc[rr][0] += av * w0.x; acc[rr][1] += av * w0.y;
                    acc[rr][2] += av * w0.z; acc[rr][3] += av * w0.w;
                    acc[rr][4] += av * w1.x; acc[rr][5] += av * w1.y;
                    acc[rr][6] += av * w1.z; acc[rr][7] += av * w1.w;
                }
            }
        }
    }
#pragma unroll
    for (int rr = 0; rr < 4; rr++) {
        int r = r0 + tr + rr * 16;
        if (r < n) {
            float di = dinv[r];
            float o[8];
#pragma unroll
            for (int q = 0; q < 8; q++) o[q] = acc[rr][q] * di;
            C[(size_t)r * 16 + tc] = f_to_h8(o);
        }
    }
}

// ---- wave per node; T fp16 pre-scaled by dinv; 4 edges/iter, 16 lanes/edge ----
__global__ __launch_bounds__(256) void aggregate(const uint4* __restrict__ T,
                                                 const int* __restrict__ csr,
                                                 const int* __restrict__ rowptr,
                                                 const float* __restrict__ dinv,
                                                 const float* __restrict__ bias,
                                                 uint4* __restrict__ Out, int n) {
    int node = (int)((blockIdx.x * 256 + threadIdx.x) >> 6);
    int lane = threadIdx.x & 63;
    if (node >= n) return;
    int grp = lane >> 4, m = lane & 15;

    float acc[8] = {};
    int beg = rowptr[node], end = rowptr[node + 1];
    int e = beg;
    while (e < end) {
        int take = min(end - e, 64);
        int myidx = (lane < take) ? csr[e + lane] : 0;
#pragma unroll 4
        for (int j = 0; j < take; j += 4) {
            int src = __shfl(myidx, j + grp);
            if (j + grp < take) {
                uint4 v = T[(size_t)src * 16 + m];
                float f[8];
                h8_to_f(v, f);
#pragma unroll
                for (int q = 0; q < 8; q++) acc[q] += f[q];
            }
        }
        e += take;
    }
#pragma unroll
    for (int q = 0; q < 8; q++) {
        acc[q] += __shfl_xor(acc[q], 16);
        acc[q] += __shfl_xor(acc[q], 32);
    }

    float di = dinv[node];
    float self[8];
    h8_to_f(T[(size_t)node * 16 + m], self);
    const float4* bp = (const float4*)&bias[m * 8];
    float4 b0 = bp[0], b1 = bp[1];
    float bb[8] = {b0.x, b0.y, b0.z, b0.w, b1.x, b1.y, b1.z, b1.w};
    float o[8];
#pragma unroll
    for (int q = 0; q < 8; q++) o[q] = tanhf((acc[q] + self[q]) * di + bb[q]);
    if (grp == 0) Out[(size_t)node * 16 + m] = f_to_h8(o);
}

// ---- same, fused with classifier head ----
__global__ __launch_bounds__(256) void aggregate_logits(const uint4* __restrict__ T,
                                                        const int* __restrict__ csr,
                                                        const int* __restrict__ rowptr,
                                                        const float* __restrict__ dinv,
                                                        const float* __restrict__ bias,
                                                        const float* __restrict__ Wc,
                                                        const float* __restrict__ bc,
                                                        float* __restrict__ logits, int n) {
    int node = (int)((blockIdx.x * 256 + threadIdx.x) >> 6);
    int lane = threadIdx.x & 63;
    if (node >= n) return;
    int grp = lane >> 4, m = lane & 15;

    float acc[8] = {};
    int beg = rowptr[node], end = rowptr[node + 1];
    int e = beg;
    while (e < end) {
        int take = min(end - e, 64);
        int myidx = (lane < take) ? csr[e + lane] : 0;
#pragma unroll 4
        for (int j = 0; j < take; j += 4) {
            int src = __shfl(myidx, j + grp);
            if (j + grp < take) {
                uint4 v = T[(size_t)src * 16 + m];
                float f[8];
                h8_to_f(v, f);
#pragma unroll
                for (int q = 0; q < 8; q++) acc[q] += f[q];
            }
        }
        e += take;
    }
#pragma unroll
    for (int q = 0; q < 8; q++) {
        acc[q] += __shfl_xor(acc[q], 16);
        acc[q] += __shfl_xor(acc[q], 32);
    }

    float di = dinv[node];
    float self[8];
    h8_to_f(T[(size_t)node * 16 + m], self);
    const float4* bp = (const float4*)&bias[m * 8];
    float4 b0 = bp[0], b1 = bp[1];
    float bb[8] = {b0.x, b0.y, b0.z, b0.w, b1.x, b1.y, b1.z, b1.w};
    const float4* wp = (const float4*)&Wc[m * 8];
    float4 w0 = wp[0], w1 = wp[1];
    float ww[8] = {w0.x, w0.y, w0.z, w0.w, w1.x, w1.y, w1.z, w1.w};
    float d = 0.0f;
#pragma unroll
    for (int q = 0; q < 8; q++) d += tanhf((acc[q] + self[q]) * di + bb[q]) * ww[q];
#pragma unroll
    for (int off = 8; off; off >>= 1) d += __shfl_xor(d, off);
    if (lane == 0) logits[node] = d + bc[0];
}

__global__ __launch_bounds__(256) void maxpart(const float* __restrict__ logits, int n,
                                               float* __restrict__ partialMax,
                                               float* __restrict__ denom) {
    if (blockIdx.x == 0 && threadIdx.x == 0) *denom = 0.0f;
    __shared__ float s[256];
    float m = -3.4e38f;
    for (int i = blockIdx.x * 256 + threadIdx.x; i < n; i += 256 * 256)
        m = fmaxf(m, logits[i]);
    s[threadIdx.x] = m;
    __syncthreads();
    for (int d = 128; d; d >>= 1) {
        if (threadIdx.x < d) s[threadIdx.x] = fmaxf(s[threadIdx.x], s[threadIdx.x + d]);
        __syncthreads();
    }
    if (threadIdx.x == 0) partialMax[blockIdx.x] = s[0];
}

__global__ __launch_bounds__(256) void exp_kernel(const float* __restrict__ logits,
                                                  const float* __restrict__ partialMax,
                                                  float* __restrict__ outv,
                                                  float* __restrict__ denom, int n) {
    __shared__ float s[256];
    s[threadIdx.x] = partialMax[threadIdx.x];
    __syncthreads();
    for (int d = 128; d; d >>= 1) {
        if (threadIdx.x < d) s[threadIdx.x] = fmaxf(s[threadIdx.x], s[threadIdx.x + d]);
        __syncthreads();
    }
    float maxv = s[0];
    __syncthreads();
    int i = blockIdx.x * 256 + threadIdx.x;
    float e = 0.0f;
    if (i < n) {
        e = expf(logits[i] - maxv);
        outv[i] = e;
    }
    s[threadIdx.x] = e;
    __syncthreads();
    for (int d = 128; d; d >>= 1) {
        if (threadIdx.x < d) s[threadIdx.x] += s[threadIdx.x + d];
        __syncthreads();
    }
    if (threadIdx.x == 0) atomicAdd(denom, s[0]);
}

__global__ __launch_bounds__(256) void norm_kernel(float* __restrict__ out,
                                                   const float* __restrict__ denom, int n) {
    int i = blockIdx.x * 256 + threadIdx.x;
    if (i < n) out[i] = out[i] / (*denom);
}

extern "C" void kernel_launch(void* const* d_in, const int* in_sizes, int n_in,
                              void* d_out, int out_size, void* d_ws, size_t ws_size,
                              hipStream_t stream) {
    const float* x  = (const float*)d_in[0];
    const int*   ei = (const int*)d_in[1];   // [2,E] int32 (JAX x64 disabled)
    const float* W1 = (const float*)d_in[2];
    const float* b1 = (const float*)d_in[3];
    const float* W2 = (const float*)d_in[4];
    const float* b2 = (const float*)d_in[5];
    const float* Wc = (const float*)d_in[6];
    const float* bc = (const float*)d_in[7];

    int n = in_sizes[0] / 128;
    int E = in_sizes[1] / 2;
    const int* row = ei;
    const int* col = ei + E;
    int NB = (n + BSPAN - 1) >> BSHIFT;   // 196 for n=100000 (requires n <= 131072)

    char* ws = (char*)d_ws;
    size_t off = 0;
    auto alloc = [&](size_t bytes) -> void* {
        void* p = ws + off;
        off += (bytes + 255) & ~(size_t)255;
        return p;
    };
    uint4*  A        = (uint4*)alloc((size_t)n * 128 * 2);   // fp16 features
    uint4*  B        = (uint4*)alloc((size_t)n * 128 * 2);   // fp16 features
    uint2*  pairs    = (uint2*)alloc((size_t)E * 8);
    int*    csr      = (int*)alloc((size_t)E * 4);
    float*  dinv     = (float*)alloc((size_t)n * 4);
    int*    rowptr   = (int*)alloc((size_t)(n + 1) * 4);
    int*    bucketCnt= (int*)alloc(256 * 4);
    int*    bucketPtr= (int*)alloc(257 * 4);
    int*    cursor   = (int*)alloc(256 * 4);
    float*  logits   = (float*)alloc((size_t)n * 4);
    float*  pmax     = (float*)alloc(256 * 4);
    float*  denom    = (float*)alloc(4);

    int nbN = (n + 255) / 256;
    int nbW = (n + 3) / 4;  // 4 waves (nodes) per 256-thread block

    hipMemsetAsync(bucketCnt, 0, 256 * 4, stream);

    hist_buckets<<<512, 256, 0, stream>>>(col, E, bucketCnt);
    scan_buckets<<<1, 256, 0, stream>>>(bucketCnt, bucketPtr, cursor, NB, E);
    partition_edges<<<(E + PCHUNK - 1) / PCHUNK, 256, 0, stream>>>(row, col, E, cursor, pairs);
    build_bucket_csr<<<NB, 256, 0, stream>>>(pairs, bucketPtr, rowptr, dinv, csr, n, NB, E);

    gemm128<false><<<(n + 63) / 64, 256, 0, stream>>>(x, W1, dinv, A, n);
    aggregate<<<nbW, 256, 0, stream>>>(A, csr, rowptr, dinv, b1, B, n);
    gemm128<true><<<(n + 63) / 64, 256, 0, stream>>>(B, W2, dinv, A, n);
    aggregate_logits<<<nbW, 256, 0, stream>>>(A, csr, rowptr, dinv, b2, Wc, bc, logits, n);

    maxpart<<<256, 256, 0, stream>>>(logits, n, pmax, denom);
    exp_kernel<<<nbN, 256, 0, stream>>>(logits, pmax, (float*)d_out, denom, n);
    norm_kernel<<<nbN, 256, 0, stream>>>((float*)d_out, denom, n);
}

// Round 6
// 254.724 us; speedup vs baseline: 7.0355x; 1.3531x over previous
//
#include <hip/hip_runtime.h>
#include <hip/hip_fp16.h>

// GCN: 2x (linear -> deg-normalized scatter-add -> bias -> tanh) -> linear(1) -> softmax(N)
// R5: GEMMs moved to fp16 MFMA (16x16x32), W pre-packed into B-fragment layout
// (L1-resident, no LDS -> no bank conflicts). CSR bucket-sort build unchanged.

#define BSHIFT 9
#define BSPAN  512
#define PCHUNK 4096
#define LCAP   12288

typedef _Float16 half8 __attribute__((ext_vector_type(8)));
typedef float floatx4 __attribute__((ext_vector_type(4)));

__device__ inline void h8_to_f(uint4 v, float* f) {
    float2 p;
    p = __half22float2(__builtin_bit_cast(__half2, v.x)); f[0] = p.x; f[1] = p.y;
    p = __half22float2(__builtin_bit_cast(__half2, v.y)); f[2] = p.x; f[3] = p.y;
    p = __half22float2(__builtin_bit_cast(__half2, v.z)); f[4] = p.x; f[5] = p.y;
    p = __half22float2(__builtin_bit_cast(__half2, v.w)); f[6] = p.x; f[7] = p.y;
}

__device__ inline uint4 f_to_h8(const float* f) {
    uint4 v;
    v.x = __builtin_bit_cast(unsigned int, __floats2half2_rn(f[0], f[1]));
    v.y = __builtin_bit_cast(unsigned int, __floats2half2_rn(f[2], f[3]));
    v.z = __builtin_bit_cast(unsigned int, __floats2half2_rn(f[4], f[5]));
    v.w = __builtin_bit_cast(unsigned int, __floats2half2_rn(f[6], f[7]));
    return v;
}

// ---------------- CSR build (2-level bucket counting sort) ----------------
__global__ __launch_bounds__(256) void hist_buckets(const int* __restrict__ col, int E,
                                                    int* __restrict__ bucketCnt) {
    __shared__ int h[256];
    h[threadIdx.x] = 0;
    __syncthreads();
    for (int e = blockIdx.x * 256 + threadIdx.x; e < E; e += gridDim.x * 256)
        atomicAdd(&h[col[e] >> BSHIFT], 1);
    __syncthreads();
    int v = h[threadIdx.x];
    if (v) atomicAdd(&bucketCnt[threadIdx.x], v);
}

__global__ void scan_buckets(const int* __restrict__ cnt, int* __restrict__ bucketPtr,
                             int* __restrict__ cursor, int NB, int E) {
    __shared__ int s[256];
    int t = threadIdx.x;
    int v = (t < NB) ? cnt[t] : 0;
    s[t] = v;
    __syncthreads();
    for (int d = 1; d < 256; d <<= 1) {
        int x = (t >= d) ? s[t - d] : 0;
        __syncthreads();
        s[t] += x;
        __syncthreads();
    }
    if (t < NB) {
        int p = s[t] - v;
        bucketPtr[t] = p;
        cursor[t] = p;
    }
    if (t == 0) bucketPtr[NB] = E;
}

__global__ __launch_bounds__(256) void partition_edges(const int* __restrict__ row,
                                                       const int* __restrict__ col, int E,
                                                       int* __restrict__ cursor,
                                                       uint2* __restrict__ pairs) {
    __shared__ int hist[256], sscan[256], gdelta[256], hcur[256];
    __shared__ uint2 stage[PCHUNK];
    int t = threadIdx.x;
    int base = blockIdx.x * PCHUNK;
    int cnt = min(PCHUNK, E - base);
    hist[t] = 0;
    __syncthreads();
    uint2 v[16];
    int b_[16];
#pragma unroll
    for (int k = 0; k < 16; k++) {
        int idx = t + k * 256;
        if (idx < cnt) {
            int c = col[base + idx], r = row[base + idx];
            v[k] = make_uint2((unsigned)c, (unsigned)r);
            b_[k] = c >> BSHIFT;
            atomicAdd(&hist[b_[k]], 1);
        } else b_[k] = -1;
    }
    __syncthreads();
    int hv = hist[t];
    sscan[t] = hv;
    __syncthreads();
    for (int d = 1; d < 256; d <<= 1) {
        int x = (t >= d) ? sscan[t - d] : 0;
        __syncthreads();
        sscan[t] += x;
        __syncthreads();
    }
    int excl = sscan[t] - hv;
    if (hv > 0) {
        int g = atomicAdd(&cursor[t], hv);
        gdelta[t] = g - excl;
    }
    hcur[t] = excl;
    __syncthreads();
#pragma unroll
    for (int k = 0; k < 16; k++) {
        if (b_[k] >= 0) {
            int slot = atomicAdd(&hcur[b_[k]], 1);
            stage[slot] = v[k];
        }
    }
    __syncthreads();
    for (int i = t; i < cnt; i += 256) {
        uint2 p = stage[i];
        pairs[gdelta[p.x >> BSHIFT] + i] = p;
    }
}

__global__ __launch_bounds__(256) void build_bucket_csr(const uint2* __restrict__ pairs,
                                                        const int* __restrict__ bucketPtr,
                                                        int* __restrict__ rowptr,
                                                        float* __restrict__ dinv,
                                                        int* __restrict__ csr,
                                                        int n, int NB, int E) {
    __shared__ int hist[BSPAN];
    __shared__ int lptr[BSPAN];
    __shared__ int s[256];
    __shared__ int srcStage[LCAP];
    int b = blockIdx.x, t = threadIdx.x;
    int base = bucketPtr[b], cnt = bucketPtr[b + 1] - base;
    int node0 = b << BSHIFT;
    int nn = min(BSPAN, n - node0);
    hist[t] = 0; hist[t + 256] = 0;
    __syncthreads();
    for (int i = t; i < cnt; i += 256)
        atomicAdd(&hist[pairs[base + i].x & (BSPAN - 1)], 1);
    __syncthreads();
    int a0 = hist[2 * t], a1 = hist[2 * t + 1];
    int sum = a0 + a1;
    s[t] = sum;
    __syncthreads();
    for (int d = 1; d < 256; d <<= 1) {
        int x = (t >= d) ? s[t - d] : 0;
        __syncthreads();
        s[t] += x;
        __syncthreads();
    }
    int excl = s[t] - sum;
    lptr[2 * t] = excl;
    lptr[2 * t + 1] = excl + a0;
    __syncthreads();
    for (int lc = t; lc < nn; lc += 256) {
        rowptr[node0 + lc] = base + lptr[lc];
        dinv[node0 + lc] = rsqrtf((float)(hist[lc] + 1));
    }
    if (b == NB - 1 && t == 0) rowptr[n] = E;
    __syncthreads();
    hist[t] = 0; hist[t + 256] = 0;
    __syncthreads();
    bool inLds = (cnt <= LCAP);
    for (int i = t; i < cnt; i += 256) {
        uint2 p = pairs[base + i];
        int lc = p.x & (BSPAN - 1);
        int rank = atomicAdd(&hist[lc], 1);
        int slot = lptr[lc] + rank;
        if (inLds) srcStage[slot] = (int)p.y;
        else csr[base + slot] = (int)p.y;
    }
    __syncthreads();
    if (inLds)
        for (int i = t; i < cnt; i += 256) csr[base + i] = srcStage[i];
}

// ---------------- W -> B-fragment layout (fp16) ----------------
// F[ks][ct][lane] = 8 fp16: W[ks*32 + (lane>>4)*8 + j][ct*16 + (lane&15)], j=0..7
__global__ __launch_bounds__(256) void prep_wfrags(const float* __restrict__ W,
                                                   uint4* __restrict__ F) {
    int t = blockIdx.x * 256 + threadIdx.x;   // 0..2047
    if (t >= 2048) return;
    int lane = t & 63, ct = (t >> 6) & 7, ks = t >> 9;
    int col = ct * 16 + (lane & 15);
    int kb = ks * 32 + (lane >> 4) * 8;
    half8 v;
#pragma unroll
    for (int j = 0; j < 8; j++) v[j] = (_Float16)W[(kb + j) * 128 + col];
    F[t] = __builtin_bit_cast(uint4, v);
}

// ---------------- MFMA GEMM: C[r,:] = fp16( dinv[r] * (A[r,:] @ W) ) ----------------
// block = 128 rows, 4 waves; wave = 32 rows x 128 cols; 16x16x32 f16 MFMA.
template <bool HALF_IN>
__global__ __launch_bounds__(256) void gemm_mfma(const void* __restrict__ Ap,
                                                 const uint4* __restrict__ F,
                                                 const float* __restrict__ dinv,
                                                 unsigned short* __restrict__ C, int n) {
    int w = threadIdx.x >> 6, lane = threadIdx.x & 63;
    int r0 = blockIdx.x * 128 + w * 32;
    int rA0 = r0 + (lane & 15);
    int rA1 = rA0 + 16;
    int kc = lane >> 4;                 // k-chunk within k-step (0..3)
    floatx4 acc[2][8] = {};

#pragma unroll
    for (int ks = 0; ks < 4; ks++) {
        half8 a0 = {}, a1 = {};
        if constexpr (HALF_IN) {
            const uint4* A4 = (const uint4*)Ap;
            if (rA0 < n) a0 = __builtin_bit_cast(half8, A4[(size_t)rA0 * 16 + ks * 4 + kc]);
            if (rA1 < n) a1 = __builtin_bit_cast(half8, A4[(size_t)rA1 * 16 + ks * 4 + kc]);
        } else {
            const float* Af = (const float*)Ap;
            if (rA0 < n) {
                const float4* p = (const float4*)&Af[(size_t)rA0 * 128 + ks * 32 + kc * 8];
                float4 u = p[0], v = p[1];
                a0[0] = (_Float16)u.x; a0[1] = (_Float16)u.y; a0[2] = (_Float16)u.z; a0[3] = (_Float16)u.w;
                a0[4] = (_Float16)v.x; a0[5] = (_Float16)v.y; a0[6] = (_Float16)v.z; a0[7] = (_Float16)v.w;
            }
            if (rA1 < n) {
                const float4* p = (const float4*)&Af[(size_t)rA1 * 128 + ks * 32 + kc * 8];
                float4 u = p[0], v = p[1];
                a1[0] = (_Float16)u.x; a1[1] = (_Float16)u.y; a1[2] = (_Float16)u.z; a1[3] = (_Float16)u.w;
                a1[4] = (_Float16)v.x; a1[5] = (_Float16)v.y; a1[6] = (_Float16)v.z; a1[7] = (_Float16)v.w;
            }
        }
        half8 b[8];
#pragma unroll
        for (int ct = 0; ct < 8; ct++)
            b[ct] = __builtin_bit_cast(half8, F[ks * 512 + ct * 64 + lane]);
#pragma unroll
        for (int ct = 0; ct < 8; ct++) {
            acc[0][ct] = __builtin_amdgcn_mfma_f32_16x16x32_f16(a0, b[ct], acc[0][ct], 0, 0, 0);
            acc[1][ct] = __builtin_amdgcn_mfma_f32_16x16x32_f16(a1, b[ct], acc[1][ct], 0, 0, 0);
        }
    }

    // epilogue: C/D layout col=lane&15, row=(lane>>4)*4+reg
#pragma unroll
    for (int rt = 0; rt < 2; rt++) {
        int rbase = r0 + rt * 16 + (lane >> 4) * 4;
#pragma unroll
        for (int reg = 0; reg < 4; reg++) {
            int r = rbase + reg;
            if (r < n) {
                float di = dinv[r];
#pragma unroll
                for (int ct = 0; ct < 8; ct++) {
                    _Float16 h = (_Float16)(acc[rt][ct][reg] * di);
                    C[(size_t)r * 128 + ct * 16 + (lane & 15)] =
                        __builtin_bit_cast(unsigned short, h);
                }
            }
        }
    }
}

// ---------------- aggregation (unchanged from R4) ----------------
__global__ __launch_bounds__(256) void aggregate(const uint4* __restrict__ T,
                                                 const int* __restrict__ csr,
                                                 const int* __restrict__ rowptr,
                                                 const float* __restrict__ dinv,
                                                 const float* __restrict__ bias,
                                                 uint4* __restrict__ Out, int n) {
    int node = (int)((blockIdx.x * 256 + threadIdx.x) >> 6);
    int lane = threadIdx.x & 63;
    if (node >= n) return;
    int grp = lane >> 4, m = lane & 15;

    float acc[8] = {};
    int beg = rowptr[node], end = rowptr[node + 1];
    int e = beg;
    while (e < end) {
        int take = min(end - e, 64);
        int myidx = (lane < take) ? csr[e + lane] : 0;
#pragma unroll 4
        for (int j = 0; j < take; j += 4) {
            int src = __shfl(myidx, j + grp);
            if (j + grp < take) {
                uint4 v = T[(size_t)src * 16 + m];
                float f[8];
                h8_to_f(v, f);
#pragma unroll
                for (int q = 0; q < 8; q++) acc[q] += f[q];
            }
        }
        e += take;
    }
#pragma unroll
    for (int q = 0; q < 8; q++) {
        acc[q] += __shfl_xor(acc[q], 16);
        acc[q] += __shfl_xor(acc[q], 32);
    }

    float di = dinv[node];
    float self[8];
    h8_to_f(T[(size_t)node * 16 + m], self);
    const float4* bp = (const float4*)&bias[m * 8];
    float4 b0 = bp[0], b1 = bp[1];
    float bb[8] = {b0.x, b0.y, b0.z, b0.w, b1.x, b1.y, b1.z, b1.w};
    float o[8];
#pragma unroll
    for (int q = 0; q < 8; q++) o[q] = tanhf((acc[q] + self[q]) * di + bb[q]);
    if (grp == 0) Out[(size_t)node * 16 + m] = f_to_h8(o);
}

__global__ __launch_bounds__(256) void aggregate_logits(const uint4* __restrict__ T,
                                                        const int* __restrict__ csr,
                                                        const int* __restrict__ rowptr,
                                                        const float* __restrict__ dinv,
                                                        const float* __restrict__ bias,
                                                        const float* __restrict__ Wc,
                                                        const float* __restrict__ bc,
                                                        float* __restrict__ logits, int n) {
    int node = (int)((blockIdx.x * 256 + threadIdx.x) >> 6);
    int lane = threadIdx.x & 63;
    if (node >= n) return;
    int grp = lane >> 4, m = lane & 15;

    float acc[8] = {};
    int beg = rowptr[node], end = rowptr[node + 1];
    int e = beg;
    while (e < end) {
        int take = min(end - e, 64);
        int myidx = (lane < take) ? csr[e + lane] : 0;
#pragma unroll 4
        for (int j = 0; j < take; j += 4) {
            int src = __shfl(myidx, j + grp);
            if (j + grp < take) {
                uint4 v = T[(size_t)src * 16 + m];
                float f[8];
                h8_to_f(v, f);
#pragma unroll
                for (int q = 0; q < 8; q++) acc[q] += f[q];
            }
        }
        e += take;
    }
#pragma unroll
    for (int q = 0; q < 8; q++) {
        acc[q] += __shfl_xor(acc[q], 16);
        acc[q] += __shfl_xor(acc[q], 32);
    }

    float di = dinv[node];
    float self[8];
    h8_to_f(T[(size_t)node * 16 + m], self);
    const float4* bp = (const float4*)&bias[m * 8];
    float4 b0 = bp[0], b1 = bp[1];
    float bb[8] = {b0.x, b0.y, b0.z, b0.w, b1.x, b1.y, b1.z, b1.w};
    const float4* wp = (const float4*)&Wc[m * 8];
    float4 w0 = wp[0], w1 = wp[1];
    float ww[8] = {w0.x, w0.y, w0.z, w0.w, w1.x, w1.y, w1.z, w1.w};
    float d = 0.0f;
#pragma unroll
    for (int q = 0; q < 8; q++) d += tanhf((acc[q] + self[q]) * di + bb[q]) * ww[q];
#pragma unroll
    for (int off = 8; off; off >>= 1) d += __shfl_xor(d, off);
    if (lane == 0) logits[node] = d + bc[0];
}

// ---------------- softmax over N ----------------
__global__ __launch_bounds__(256) void maxpart(const float* __restrict__ logits, int n,
                                               float* __restrict__ partialMax,
                                               float* __restrict__ denom) {
    if (blockIdx.x == 0 && threadIdx.x == 0) *denom = 0.0f;
    __shared__ float s[256];
    float m = -3.4e38f;
    for (int i = blockIdx.x * 256 + threadIdx.x; i < n; i += 256 * 256)
        m = fmaxf(m, logits[i]);
    s[threadIdx.x] = m;
    __syncthreads();
    for (int d = 128; d; d >>= 1) {
        if (threadIdx.x < d) s[threadIdx.x] = fmaxf(s[threadIdx.x], s[threadIdx.x + d]);
        __syncthreads();
    }
    if (threadIdx.x == 0) partialMax[blockIdx.x] = s[0];
}

__global__ __launch_bounds__(256) void exp_kernel(const float* __restrict__ logits,
                                                  const float* __restrict__ partialMax,
                                                  float* __restrict__ outv,
                                                  float* __restrict__ denom, int n) {
    __shared__ float s[256];
    s[threadIdx.x] = partialMax[threadIdx.x];
    __syncthreads();
    for (int d = 128; d; d >>= 1) {
        if (threadIdx.x < d) s[threadIdx.x] = fmaxf(s[threadIdx.x], s[threadIdx.x + d]);
        __syncthreads();
    }
    float maxv = s[0];
    __syncthreads();
    int i = blockIdx.x * 256 + threadIdx.x;
    float e = 0.0f;
    if (i < n) {
        e = expf(logits[i] - maxv);
        outv[i] = e;
    }
    s[threadIdx.x] = e;
    __syncthreads();
    for (int d = 128; d; d >>= 1) {
        if (threadIdx.x < d) s[threadIdx.x] += s[threadIdx.x + d];
        __syncthreads();
    }
    if (threadIdx.x == 0) atomicAdd(denom, s[0]);
}

__global__ __launch_bounds__(256) void norm_kernel(float* __restrict__ out,
                                                   const float* __restrict__ denom, int n) {
    int i = blockIdx.x * 256 + threadIdx.x;
    if (i < n) out[i] = out[i] / (*denom);
}

extern "C" void kernel_launch(void* const* d_in, const int* in_sizes, int n_in,
                              void* d_out, int out_size, void* d_ws, size_t ws_size,
                              hipStream_t stream) {
    const float* x  = (const float*)d_in[0];
    const int*   ei = (const int*)d_in[1];   // [2,E] int32 (JAX x64 disabled)
    const float* W1 = (const float*)d_in[2];
    const float* b1 = (const float*)d_in[3];
    const float* W2 = (const float*)d_in[4];
    const float* b2 = (const float*)d_in[5];
    const float* Wc = (const float*)d_in[6];
    const float* bc = (const float*)d_in[7];

    int n = in_sizes[0] / 128;
    int E = in_sizes[1] / 2;
    const int* row = ei;
    const int* col = ei + E;
    int NB = (n + BSPAN - 1) >> BSHIFT;   // 196 for n=100000

    char* ws = (char*)d_ws;
    size_t off = 0;
    auto alloc = [&](size_t bytes) -> void* {
        void* p = ws + off;
        off += (bytes + 255) & ~(size_t)255;
        return p;
    };
    uint4*  A        = (uint4*)alloc((size_t)n * 128 * 2);   // fp16 features
    uint4*  B        = (uint4*)alloc((size_t)n * 128 * 2);   // fp16 features
    uint2*  pairs    = (uint2*)alloc((size_t)E * 8);
    int*    csr      = (int*)alloc((size_t)E * 4);
    float*  dinv     = (float*)alloc((size_t)n * 4);
    int*    rowptr   = (int*)alloc((size_t)(n + 1) * 4);
    int*    bucketCnt= (int*)alloc(256 * 4);
    int*    bucketPtr= (int*)alloc(257 * 4);
    int*    cursor   = (int*)alloc(256 * 4);
    uint4*  F1       = (uint4*)alloc(2048 * 16);
    uint4*  F2       = (uint4*)alloc(2048 * 16);
    float*  logits   = (float*)alloc((size_t)n * 4);
    float*  pmax     = (float*)alloc(256 * 4);
    float*  denom    = (float*)alloc(4);

    int nbN = (n + 255) / 256;
    int nbW = (n + 3) / 4;

    hipMemsetAsync(bucketCnt, 0, 256 * 4, stream);

    hist_buckets<<<512, 256, 0, stream>>>(col, E, bucketCnt);
    scan_buckets<<<1, 256, 0, stream>>>(bucketCnt, bucketPtr, cursor, NB, E);
    partition_edges<<<(E + PCHUNK - 1) / PCHUNK, 256, 0, stream>>>(row, col, E, cursor, pairs);
    prep_wfrags<<<8, 256, 0, stream>>>(W1, F1);
    prep_wfrags<<<8, 256, 0, stream>>>(W2, F2);
    build_bucket_csr<<<NB, 256, 0, stream>>>(pairs, bucketPtr, rowptr, dinv, csr, n, NB, E);

    int nbG = (n + 127) / 128;
    gemm_mfma<false><<<nbG, 256, 0, stream>>>(x, F1, dinv, (unsigned short*)A, n);
    aggregate<<<nbW, 256, 0, stream>>>(A, csr, rowptr, dinv, b1, B, n);
    gemm_mfma<true><<<nbG, 256, 0, stream>>>(B, F2, dinv, (unsigned short*)A, n);
    aggregate_logits<<<nbW, 256, 0, stream>>>(A, csr, rowptr, dinv, b2, Wc, bc, logits, n);

    maxpart<<<256, 256, 0, stream>>>(logits, n, pmax, denom);
    exp_kernel<<<nbN, 256, 0, stream>>>(logits, pmax, (float*)d_out, denom, n);
    norm_kernel<<<nbN, 256, 0, stream>>>((float*)d_out, denom, n);
}

// Round 7
// 251.732 us; speedup vs baseline: 7.1191x; 1.0119x over previous
//
#include <hip/hip_runtime.h>
#include <hip/hip_fp16.h>

// GCN: 2x (linear -> deg-normalized scatter-add -> bias -> tanh) -> linear(1) -> softmax(N)
// R6: aggregate VALU diet — v_fma_mix_f32 fp16->fp32 fused accumulate (halves inner
// loop), branch-free tanh (exp+rcp, ~6 instrs vs ~25 for OCML tanhf), u32-packed
// partition pairs. MFMA GEMM + bucket-sort CSR unchanged.

#define BSHIFT 9
#define BSPAN  512
#define PCHUNK 4096
#define LCAP   12288

typedef _Float16 half8 __attribute__((ext_vector_type(8)));
typedef float floatx4 __attribute__((ext_vector_type(4)));

__device__ inline void fmix2(float& a0, float& a1, unsigned int h2) {
    asm("v_fma_mix_f32 %0, %1, 1.0, %0 op_sel:[0,0,0] op_sel_hi:[1,0,0]" : "+v"(a0) : "v"(h2));
    asm("v_fma_mix_f32 %0, %1, 1.0, %0 op_sel:[1,0,0] op_sel_hi:[1,0,0]" : "+v"(a1) : "v"(h2));
}
__device__ inline void fmix_acc8(float* acc, uint4 v) {
    fmix2(acc[0], acc[1], v.x);
    fmix2(acc[2], acc[3], v.y);
    fmix2(acc[4], acc[5], v.z);
    fmix2(acc[6], acc[7], v.w);
}

// exact-saturating fast tanh: 1 - 2/(e^2x + 1); rcp approx err ~1e-7 << fp16 eps
__device__ inline float tanh_fast(float x) {
    float e = __expf(2.0f * x);
    return 1.0f - 2.0f * __builtin_amdgcn_rcpf(e + 1.0f);
}

__device__ inline uint4 f_to_h8(const float* f) {
    uint4 v;
    v.x = __builtin_bit_cast(unsigned int, __floats2half2_rn(f[0], f[1]));
    v.y = __builtin_bit_cast(unsigned int, __floats2half2_rn(f[2], f[3]));
    v.z = __builtin_bit_cast(unsigned int, __floats2half2_rn(f[4], f[5]));
    v.w = __builtin_bit_cast(unsigned int, __floats2half2_rn(f[6], f[7]));
    return v;
}

// ---------------- CSR build (2-level bucket counting sort) ----------------
__global__ __launch_bounds__(256) void hist_buckets(const int* __restrict__ col, int E,
                                                    int* __restrict__ bucketCnt) {
    __shared__ int h[256];
    h[threadIdx.x] = 0;
    __syncthreads();
    for (int e = blockIdx.x * 256 + threadIdx.x; e < E; e += gridDim.x * 256)
        atomicAdd(&h[col[e] >> BSHIFT], 1);
    __syncthreads();
    int v = h[threadIdx.x];
    if (v) atomicAdd(&bucketCnt[threadIdx.x], v);
}

__global__ void scan_buckets(const int* __restrict__ cnt, int* __restrict__ bucketPtr,
                             int* __restrict__ cursor, int NB, int E) {
    __shared__ int s[256];
    int t = threadIdx.x;
    int v = (t < NB) ? cnt[t] : 0;
    s[t] = v;
    __syncthreads();
    for (int d = 1; d < 256; d <<= 1) {
        int x = (t >= d) ? s[t - d] : 0;
        __syncthreads();
        s[t] += x;
        __syncthreads();
    }
    if (t < NB) {
        int p = s[t] - v;
        bucketPtr[t] = p;
        cursor[t] = p;
    }
    if (t == 0) bucketPtr[NB] = E;
}

// pairs packed: (src << BSHIFT) | (dst & (BSPAN-1))   [src < 2^23]
__global__ __launch_bounds__(256) void partition_edges(const int* __restrict__ row,
                                                       const int* __restrict__ col, int E,
                                                       int* __restrict__ cursor,
                                                       unsigned int* __restrict__ pairs) {
    __shared__ int hist[256], sscan[256], gdelta[256], hcur[256];
    __shared__ uint2 stage[PCHUNK];
    int t = threadIdx.x;
    int base = blockIdx.x * PCHUNK;
    int cnt = min(PCHUNK, E - base);
    hist[t] = 0;
    __syncthreads();
    uint2 v[16];
    int b_[16];
#pragma unroll
    for (int k = 0; k < 16; k++) {
        int idx = t + k * 256;
        if (idx < cnt) {
            int c = col[base + idx], r = row[base + idx];
            v[k] = make_uint2((unsigned)c, (unsigned)r);
            b_[k] = c >> BSHIFT;
            atomicAdd(&hist[b_[k]], 1);
        } else b_[k] = -1;
    }
    __syncthreads();
    int hv = hist[t];
    sscan[t] = hv;
    __syncthreads();
    for (int d = 1; d < 256; d <<= 1) {
        int x = (t >= d) ? sscan[t - d] : 0;
        __syncthreads();
        sscan[t] += x;
        __syncthreads();
    }
    int excl = sscan[t] - hv;
    if (hv > 0) {
        int g = atomicAdd(&cursor[t], hv);
        gdelta[t] = g - excl;
    }
    hcur[t] = excl;
    __syncthreads();
#pragma unroll
    for (int k = 0; k < 16; k++) {
        if (b_[k] >= 0) {
            int slot = atomicAdd(&hcur[b_[k]], 1);
            stage[slot] = v[k];
        }
    }
    __syncthreads();
    for (int i = t; i < cnt; i += 256) {
        uint2 p = stage[i];
        pairs[gdelta[p.x >> BSHIFT] + i] = (p.y << BSHIFT) | (p.x & (BSPAN - 1));
    }
}

__global__ __launch_bounds__(256) void build_bucket_csr(const unsigned int* __restrict__ pairs,
                                                        const int* __restrict__ bucketPtr,
                                                        int* __restrict__ rowptr,
                                                        float* __restrict__ dinv,
                                                        int* __restrict__ csr,
                                                        int n, int NB, int E) {
    __shared__ int hist[BSPAN];
    __shared__ int lptr[BSPAN];
    __shared__ int s[256];
    __shared__ int srcStage[LCAP];
    int b = blockIdx.x, t = threadIdx.x;
    int base = bucketPtr[b], cnt = bucketPtr[b + 1] - base;
    int node0 = b << BSHIFT;
    int nn = min(BSPAN, n - node0);
    hist[t] = 0; hist[t + 256] = 0;
    __syncthreads();
    for (int i = t; i < cnt; i += 256)
        atomicAdd(&hist[pairs[base + i] & (BSPAN - 1)], 1);
    __syncthreads();
    int a0 = hist[2 * t], a1 = hist[2 * t + 1];
    int sum = a0 + a1;
    s[t] = sum;
    __syncthreads();
    for (int d = 1; d < 256; d <<= 1) {
        int x = (t >= d) ? s[t - d] : 0;
        __syncthreads();
        s[t] += x;
        __syncthreads();
    }
    int excl = s[t] - sum;
    lptr[2 * t] = excl;
    lptr[2 * t + 1] = excl + a0;
    __syncthreads();
    for (int lc = t; lc < nn; lc += 256) {
        rowptr[node0 + lc] = base + lptr[lc];
        dinv[node0 + lc] = rsqrtf((float)(hist[lc] + 1));
    }
    if (b == NB - 1 && t == 0) rowptr[n] = E;
    __syncthreads();
    hist[t] = 0; hist[t + 256] = 0;
    __syncthreads();
    bool inLds = (cnt <= LCAP);
    for (int i = t; i < cnt; i += 256) {
        unsigned int p = pairs[base + i];
        int lc = p & (BSPAN - 1);
        int rank = atomicAdd(&hist[lc], 1);
        int slot = lptr[lc] + rank;
        if (inLds) srcStage[slot] = (int)(p >> BSHIFT);
        else csr[base + slot] = (int)(p >> BSHIFT);
    }
    __syncthreads();
    if (inLds)
        for (int i = t; i < cnt; i += 256) csr[base + i] = srcStage[i];
}

// ---------------- W -> B-fragment layout (fp16) ----------------
__global__ __launch_bounds__(256) void prep_wfrags(const float* __restrict__ W,
                                                   uint4* __restrict__ F) {
    int t = blockIdx.x * 256 + threadIdx.x;
    if (t >= 2048) return;
    int lane = t & 63, ct = (t >> 6) & 7, ks = t >> 9;
    int col = ct * 16 + (lane & 15);
    int kb = ks * 32 + (lane >> 4) * 8;
    half8 v;
#pragma unroll
    for (int j = 0; j < 8; j++) v[j] = (_Float16)W[(kb + j) * 128 + col];
    F[t] = __builtin_bit_cast(uint4, v);
}

// ---------------- MFMA GEMM: C[r,:] = fp16( dinv[r] * (A[r,:] @ W) ) ----------------
template <bool HALF_IN>
__global__ __launch_bounds__(256) void gemm_mfma(const void* __restrict__ Ap,
                                                 const uint4* __restrict__ F,
                                                 const float* __restrict__ dinv,
                                                 unsigned short* __restrict__ C, int n) {
    int w = threadIdx.x >> 6, lane = threadIdx.x & 63;
    int r0 = blockIdx.x * 128 + w * 32;
    int rA0 = r0 + (lane & 15);
    int rA1 = rA0 + 16;
    int kc = lane >> 4;
    floatx4 acc[2][8] = {};

#pragma unroll
    for (int ks = 0; ks < 4; ks++) {
        half8 a0 = {}, a1 = {};
        if constexpr (HALF_IN) {
            const uint4* A4 = (const uint4*)Ap;
            if (rA0 < n) a0 = __builtin_bit_cast(half8, A4[(size_t)rA0 * 16 + ks * 4 + kc]);
            if (rA1 < n) a1 = __builtin_bit_cast(half8, A4[(size_t)rA1 * 16 + ks * 4 + kc]);
        } else {
            const float* Af = (const float*)Ap;
            if (rA0 < n) {
                const float4* p = (const float4*)&Af[(size_t)rA0 * 128 + ks * 32 + kc * 8];
                float4 u = p[0], v = p[1];
                a0[0] = (_Float16)u.x; a0[1] = (_Float16)u.y; a0[2] = (_Float16)u.z; a0[3] = (_Float16)u.w;
                a0[4] = (_Float16)v.x; a0[5] = (_Float16)v.y; a0[6] = (_Float16)v.z; a0[7] = (_Float16)v.w;
            }
            if (rA1 < n) {
                const float4* p = (const float4*)&Af[(size_t)rA1 * 128 + ks * 32 + kc * 8];
                float4 u = p[0], v = p[1];
                a1[0] = (_Float16)u.x; a1[1] = (_Float16)u.y; a1[2] = (_Float16)u.z; a1[3] = (_Float16)u.w;
                a1[4] = (_Float16)v.x; a1[5] = (_Float16)v.y; a1[6] = (_Float16)v.z; a1[7] = (_Float16)v.w;
            }
        }
        half8 b[8];
#pragma unroll
        for (int ct = 0; ct < 8; ct++)
            b[ct] = __builtin_bit_cast(half8, F[ks * 512 + ct * 64 + lane]);
#pragma unroll
        for (int ct = 0; ct < 8; ct++) {
            acc[0][ct] = __builtin_amdgcn_mfma_f32_16x16x32_f16(a0, b[ct], acc[0][ct], 0, 0, 0);
            acc[1][ct] = __builtin_amdgcn_mfma_f32_16x16x32_f16(a1, b[ct], acc[1][ct], 0, 0, 0);
        }
    }

#pragma unroll
    for (int rt = 0; rt < 2; rt++) {
        int rbase = r0 + rt * 16 + (lane >> 4) * 4;
#pragma unroll
        for (int reg = 0; reg < 4; reg++) {
            int r = rbase + reg;
            if (r < n) {
                float di = dinv[r];
#pragma unroll
                for (int ct = 0; ct < 8; ct++) {
                    _Float16 h = (_Float16)(acc[rt][ct][reg] * di);
                    C[(size_t)r * 128 + ct * 16 + (lane & 15)] =
                        __builtin_bit_cast(unsigned short, h);
                }
            }
        }
    }
}

// ---------------- aggregation: wave/node, fma_mix accumulate, fast tanh ----------------
__global__ __launch_bounds__(256) void aggregate(const uint4* __restrict__ T,
                                                 const int* __restrict__ csr,
                                                 const int* __restrict__ rowptr,
                                                 const float* __restrict__ dinv,
                                                 const float* __restrict__ bias,
                                                 uint4* __restrict__ Out, int n) {
    int node = (int)((blockIdx.x * 256 + threadIdx.x) >> 6);
    int lane = threadIdx.x & 63;
    if (node >= n) return;
    int grp = lane >> 4, m = lane & 15;

    float acc[8] = {};
    int beg = rowptr[node], end = rowptr[node + 1];
    int e = beg;
    while (e < end) {
        int take = min(end - e, 64);
        int myidx = (lane < take) ? csr[e + lane] : 0;
#pragma unroll 4
        for (int j = 0; j < take; j += 4) {
            int src = __shfl(myidx, j + grp);
            if (j + grp < take) {
                uint4 v = T[(size_t)src * 16 + m];
                fmix_acc8(acc, v);
            }
        }
        e += take;
    }
#pragma unroll
    for (int q = 0; q < 8; q++) {
        acc[q] += __shfl_xor(acc[q], 16);
        acc[q] += __shfl_xor(acc[q], 32);
    }

    fmix_acc8(acc, T[(size_t)node * 16 + m]);   // self loop
    float di = dinv[node];
    const float4* bp = (const float4*)&bias[m * 8];
    float4 b0 = bp[0], b1 = bp[1];
    float bb[8] = {b0.x, b0.y, b0.z, b0.w, b1.x, b1.y, b1.z, b1.w};
    float o[8];
#pragma unroll
    for (int q = 0; q < 8; q++) o[q] = tanh_fast(acc[q] * di + bb[q]);
    if (grp == 0) Out[(size_t)node * 16 + m] = f_to_h8(o);
}

__global__ __launch_bounds__(256) void aggregate_logits(const uint4* __restrict__ T,
                                                        const int* __restrict__ csr,
                                                        const int* __restrict__ rowptr,
                                                        const float* __restrict__ dinv,
                                                        const float* __restrict__ bias,
                                                        const float* __restrict__ Wc,
                                                        const float* __restrict__ bc,
                                                        float* __restrict__ logits, int n) {
    int node = (int)((blockIdx.x * 256 + threadIdx.x) >> 6);
    int lane = threadIdx.x & 63;
    if (node >= n) return;
    int grp = lane >> 4, m = lane & 15;

    float acc[8] = {};
    int beg = rowptr[node], end = rowptr[node + 1];
    int e = beg;
    while (e < end) {
        int take = min(end - e, 64);
        int myidx = (lane < take) ? csr[e + lane] : 0;
#pragma unroll 4
        for (int j = 0; j < take; j += 4) {
            int src = __shfl(myidx, j + grp);
            if (j + grp < take) {
                uint4 v = T[(size_t)src * 16 + m];
                fmix_acc8(acc, v);
            }
        }
        e += take;
    }
#pragma unroll
    for (int q = 0; q < 8; q++) {
        acc[q] += __shfl_xor(acc[q], 16);
        acc[q] += __shfl_xor(acc[q], 32);
    }

    fmix_acc8(acc, T[(size_t)node * 16 + m]);   // self loop
    float di = dinv[node];
    const float4* bp = (const float4*)&bias[m * 8];
    float4 b0 = bp[0], b1 = bp[1];
    float bb[8] = {b0.x, b0.y, b0.z, b0.w, b1.x, b1.y, b1.z, b1.w};
    const float4* wp = (const float4*)&Wc[m * 8];
    float4 w0 = wp[0], w1 = wp[1];
    float ww[8] = {w0.x, w0.y, w0.z, w0.w, w1.x, w1.y, w1.z, w1.w};
    float d = 0.0f;
#pragma unroll
    for (int q = 0; q < 8; q++) d += tanh_fast(acc[q] * di + bb[q]) * ww[q];
#pragma unroll
    for (int off = 8; off; off >>= 1) d += __shfl_xor(d, off);
    if (lane == 0) logits[node] = d + bc[0];
}

// ---------------- softmax over N ----------------
__global__ __launch_bounds__(256) void maxpart(const float* __restrict__ logits, int n,
                                               float* __restrict__ partialMax,
                                               float* __restrict__ denom) {
    if (blockIdx.x == 0 && threadIdx.x == 0) *denom = 0.0f;
    __shared__ float s[256];
    float m = -3.4e38f;
    for (int i = blockIdx.x * 256 + threadIdx.x; i < n; i += 256 * 256)
        m = fmaxf(m, logits[i]);
    s[threadIdx.x] = m;
    __syncthreads();
    for (int d = 128; d; d >>= 1) {
        if (threadIdx.x < d) s[threadIdx.x] = fmaxf(s[threadIdx.x], s[threadIdx.x + d]);
        __syncthreads();
    }
    if (threadIdx.x == 0) partialMax[blockIdx.x] = s[0];
}

__global__ __launch_bounds__(256) void exp_kernel(const float* __restrict__ logits,
                                                  const float* __restrict__ partialMax,
                                                  float* __restrict__ outv,
                                                  float* __restrict__ denom, int n) {
    __shared__ float s[256];
    s[threadIdx.x] = partialMax[threadIdx.x];
    __syncthreads();
    for (int d = 128; d; d >>= 1) {
        if (threadIdx.x < d) s[threadIdx.x] = fmaxf(s[threadIdx.x], s[threadIdx.x + d]);
        __syncthreads();
    }
    float maxv = s[0];
    __syncthreads();
    int i = blockIdx.x * 256 + threadIdx.x;
    float e = 0.0f;
    if (i < n) {
        e = expf(logits[i] - maxv);
        outv[i] = e;
    }
    s[threadIdx.x] = e;
    __syncthreads();
    for (int d = 128; d; d >>= 1) {
        if (threadIdx.x < d) s[threadIdx.x] += s[threadIdx.x + d];
        __syncthreads();
    }
    if (threadIdx.x == 0) atomicAdd(denom, s[0]);
}

__global__ __launch_bounds__(256) void norm_kernel(float* __restrict__ out,
                                                   const float* __restrict__ denom, int n) {
    int i = blockIdx.x * 256 + threadIdx.x;
    if (i < n) out[i] = out[i] / (*denom);
}

extern "C" void kernel_launch(void* const* d_in, const int* in_sizes, int n_in,
                              void* d_out, int out_size, void* d_ws, size_t ws_size,
                              hipStream_t stream) {
    const float* x  = (const float*)d_in[0];
    const int*   ei = (const int*)d_in[1];   // [2,E] int32 (JAX x64 disabled)
    const float* W1 = (const float*)d_in[2];
    const float* b1 = (const float*)d_in[3];
    const float* W2 = (const float*)d_in[4];
    const float* b2 = (const float*)d_in[5];
    const float* Wc = (const float*)d_in[6];
    const float* bc = (const float*)d_in[7];

    int n = in_sizes[0] / 128;
    int E = in_sizes[1] / 2;
    const int* row = ei;
    const int* col = ei + E;
    int NB = (n + BSPAN - 1) >> BSHIFT;

    char* ws = (char*)d_ws;
    size_t off = 0;
    auto alloc = [&](size_t bytes) -> void* {
        void* p = ws + off;
        off += (bytes + 255) & ~(size_t)255;
        return p;
    };
    uint4*  A        = (uint4*)alloc((size_t)n * 128 * 2);
    uint4*  B        = (uint4*)alloc((size_t)n * 128 * 2);
    unsigned int* pairs = (unsigned int*)alloc((size_t)E * 4);
    int*    csr      = (int*)alloc((size_t)E * 4);
    float*  dinv     = (float*)alloc((size_t)n * 4);
    int*    rowptr   = (int*)alloc((size_t)(n + 1) * 4);
    int*    bucketCnt= (int*)alloc(256 * 4);
    int*    bucketPtr= (int*)alloc(257 * 4);
    int*    cursor   = (int*)alloc(256 * 4);
    uint4*  F1       = (uint4*)alloc(2048 * 16);
    uint4*  F2       = (uint4*)alloc(2048 * 16);
    float*  logits   = (float*)alloc((size_t)n * 4);
    float*  pmax     = (float*)alloc(256 * 4);
    float*  denom    = (float*)alloc(4);

    int nbN = (n + 255) / 256;
    int nbW = (n + 3) / 4;

    hipMemsetAsync(bucketCnt, 0, 256 * 4, stream);

    hist_buckets<<<512, 256, 0, stream>>>(col, E, bucketCnt);
    scan_buckets<<<1, 256, 0, stream>>>(bucketCnt, bucketPtr, cursor, NB, E);
    partition_edges<<<(E + PCHUNK - 1) / PCHUNK, 256, 0, stream>>>(row, col, E, cursor, pairs);
    prep_wfrags<<<8, 256, 0, stream>>>(W1, F1);
    prep_wfrags<<<8, 256, 0, stream>>>(W2, F2);
    build_bucket_csr<<<NB, 256, 0, stream>>>(pairs, bucketPtr, rowptr, dinv, csr, n, NB, E);

    int nbG = (n + 127) / 128;
    gemm_mfma<false><<<nbG, 256, 0, stream>>>(x, F1, dinv, (unsigned short*)A, n);
    aggregate<<<nbW, 256, 0, stream>>>(A, csr, rowptr, dinv, b1, B, n);
    gemm_mfma<true><<<nbG, 256, 0, stream>>>(B, F2, dinv, (unsigned short*)A, n);
    aggregate_logits<<<nbW, 256, 0, stream>>>(A, csr, rowptr, dinv, b2, Wc, bc, logits, n);

    maxpart<<<256, 256, 0, stream>>>(logits, n, pmax, denom);
    exp_kernel<<<nbN, 256, 0, stream>>>(logits, pmax, (float*)d_out, denom, n);
    norm_kernel<<<nbN, 256, 0, stream>>>((float*)d_out, denom, n);
}